// Round 1
// baseline (530.124 us; speedup 1.0000x reference)
//
#include <hip/hip_runtime.h>
#include <stdint.h>

#define B_     8
#define LQ_    4096
#define S_     77
#define SP_    80
#define D_     1024
#define H_     16
#define HD_    64
#define NC_    1280   // H_*SP_
#define NSUBJ_ 32

typedef __attribute__((ext_vector_type(4))) float  f4;
typedef __attribute__((ext_vector_type(8))) short  short8;
typedef __attribute__((ext_vector_type(8))) unsigned short us8;

__device__ __forceinline__ unsigned short f2bf(float f) {
  union { float f; unsigned u; } x; x.f = f;
  unsigned r = x.u + 0x7FFFu + ((x.u >> 16) & 1u);
  return (unsigned short)(r >> 16);
}

__device__ __forceinline__ void gload16(const void* g, void* s) {
  __builtin_amdgcn_global_load_lds((const __attribute__((address_space(1))) void*)g,
                                   (__attribute__((address_space(3))) void*)s, 16, 0, 0);
}

// ---------------- hssum: per-(b,d) sum of hs over l ----------------
__global__ __launch_bounds__(256) void k_hssum(const float* __restrict__ hs,
                                               float* __restrict__ hssum) {
  int b = blockIdx.y;
  size_t base = ((size_t)b * LQ_ + (size_t)blockIdx.x * 64) * D_ + threadIdx.x * 4;
  f4 acc = {0.f, 0.f, 0.f, 0.f};
  for (int l = 0; l < 64; ++l) {
    f4 v = *(const f4*)(hs + base + (size_t)l * D_);
    acc += v;
  }
  float* dst = hssum + b * D_ + threadIdx.x * 4;
  atomicAdd(dst + 0, acc[0]); atomicAdd(dst + 1, acc[1]);
  atomicAdd(dst + 2, acc[2]); atomicAdd(dst + 3, acc[3]);
}

// ---------------- transpose fp32 (R,C)->(C,R), dims %32==0 ----------------
__global__ __launch_bounds__(256) void k_tr(const float* __restrict__ in,
                                            float* __restrict__ out, int R, int C) {
  __shared__ float tile[32][33];
  int c0 = blockIdx.x * 32, r0 = blockIdx.y * 32;
  int tx = threadIdx.x & 31, ty = threadIdx.x >> 5;
#pragma unroll
  for (int k = 0; k < 4; ++k)
    tile[ty + 8 * k][tx] = in[(size_t)(r0 + ty + 8 * k) * C + c0 + tx];
  __syncthreads();
#pragma unroll
  for (int k = 0; k < 4; ++k)
    out[(size_t)(c0 + ty + 8 * k) * R + r0 + tx] = tile[tx][ty + 8 * k];
}

// ---------------- generic small GEMM: C = alpha*(A @ Bt^T) [+ Dm], bf16 MFMA ----------------
// A: fp32 [M x K] lda, rows valid < Mv (else 0). Bt: fp32 [N x K] ldb.
// z = z1*Z2+z2 offsets. K % 32 == 0.
template <bool OBF>
__global__ __launch_bounds__(256) void k_gemm_small(
    const float* __restrict__ A, int lda, long sA1, long sA2,
    const float* __restrict__ Bt, int ldb, long sB1, long sB2,
    void* __restrict__ Cv, int ldc, long sC1, long sC2,
    const float* __restrict__ Dm, int ldd,
    int M, int Mv, int N, int K, float alpha, int Z2) {
  int z = blockIdx.z, z1 = z / Z2, z2 = z - z1 * Z2;
  A  += z1 * sA1 + z2 * sA2;
  Bt += z1 * sB1 + z2 * sB2;
  long cbase = z1 * sC1 + z2 * sC2;
  __shared__ short As[64 * 40];
  __shared__ short Bs[64 * 40];
  int t = threadIdx.x, lane = t & 63, wid = t >> 6;
  int wm = wid >> 1, wn = wid & 1;
  int m0 = blockIdx.x * 64, n0 = blockIdx.y * 64;
  f4 acc[2][2] = {};
  int srow = t >> 2, skc = (t & 3) * 8;
  for (int k0 = 0; k0 < K; k0 += 32) {
    __syncthreads();
    f4 a0 = {0,0,0,0}, a1 = {0,0,0,0}, b0 = {0,0,0,0}, b1 = {0,0,0,0};
    if (m0 + srow < Mv) {
      const float* p = A + (size_t)(m0 + srow) * lda + k0 + skc;
      a0 = *(const f4*)p; a1 = *(const f4*)(p + 4);
    }
    if (n0 + srow < N) {
      const float* p = Bt + (size_t)(n0 + srow) * ldb + k0 + skc;
      b0 = *(const f4*)p; b1 = *(const f4*)(p + 4);
    }
    us8 ua, ub;
#pragma unroll
    for (int j = 0; j < 4; ++j) {
      ua[j] = f2bf(a0[j]); ua[4 + j] = f2bf(a1[j]);
      ub[j] = f2bf(b0[j]); ub[4 + j] = f2bf(b1[j]);
    }
    *(us8*)(As + srow * 40 + skc) = ua;
    *(us8*)(Bs + srow * 40 + skc) = ub;
    __syncthreads();
    short8 fa[2], fb[2];
#pragma unroll
    for (int i = 0; i < 2; ++i) {
      fa[i] = *(const short8*)(As + (wm * 32 + i * 16 + (lane & 15)) * 40 + (lane >> 4) * 8);
      fb[i] = *(const short8*)(Bs + (wn * 32 + i * 16 + (lane & 15)) * 40 + (lane >> 4) * 8);
    }
#pragma unroll
    for (int mi = 0; mi < 2; ++mi)
#pragma unroll
      for (int ni = 0; ni < 2; ++ni)
        acc[mi][ni] = __builtin_amdgcn_mfma_f32_16x16x32_bf16(fa[mi], fb[ni], acc[mi][ni], 0, 0, 0);
  }
#pragma unroll
  for (int mi = 0; mi < 2; ++mi)
#pragma unroll
    for (int ni = 0; ni < 2; ++ni)
#pragma unroll
      for (int j = 0; j < 4; ++j) {
        int row = m0 + wm * 32 + mi * 16 + (lane >> 4) * 4 + j;
        int col = n0 + wn * 32 + ni * 16 + (lane & 15);
        if (row < M && col < N) {
          float val = acc[mi][ni][j] * alpha;
          if (Dm) val += Dm[(size_t)row * ldd + col];
          size_t idx = (size_t)cbase + (size_t)row * ldc + col;
          if (OBF) ((unsigned short*)Cv)[idx] = f2bf(val);
          else     ((float*)Cv)[idx] = val;
        }
      }
}

// ---------------- mu/alpha/beta per (b,h,s) ----------------
__global__ void k_mubeta(const float* __restrict__ qmean, const float* __restrict__ kbuf,
                         const int* __restrict__ sb, const int* __restrict__ sn,
                         const float* __restrict__ csf_p,
                         float* __restrict__ alphav, float* __restrict__ betav) {
  int h = blockIdx.x, b = blockIdx.y, s = threadIdx.x;
  if (s >= SP_) return;
  const float* qp = qmean + b * D_ + h * HD_;
  const float* kp = kbuf + ((size_t)(b * SP_ + s)) * D_ + h * HD_;
  float mu = 0.f;
#pragma unroll 8
  for (int hd = 0; hd < HD_; ++hd) mu += qp[hd] * kp[hd];
  mu *= 0.125f;
  bool subj = false;
  for (int i = 0; i < NSUBJ_; ++i) subj = subj || (sb[i] == b && sn[i] == s);
  float csf = *csf_p;
  int c = b * NC_ + h * SP_ + s;
  alphav[c] = subj ? csf : 1.f;
  betav[c] = (s >= S_) ? -1e30f : (subj ? -mu * csf : 0.f);
}

// ---------------- C: score GEMM (hs fp32 @ Mt^T) + per-head softmax -> P bf16 ----------------
#define CBM 128
#define CBN 160
#define CBK 64
__global__ __launch_bounds__(256) void k_score(
    const float* __restrict__ hs, const unsigned short* __restrict__ Mt,
    const float* __restrict__ alphav, const float* __restrict__ betav,
    unsigned short* __restrict__ P) {
  // bijective XCD swizzle: 8 n-tiles of one (b,m)-panel land consecutively on one XCD
  int id = blockIdx.x;
  int x = id & 7, idp = id >> 3;
  int n_t = idp & 7;
  int pid = (idp >> 3) * 8 + x;     // [0,256)
  int b = pid >> 5, m_t = pid & 31;
  int m0 = m_t * CBM, n0 = n_t * CBN;

  const float* Ab = hs + (size_t)b * LQ_ * D_;
  const unsigned short* Bb = Mt + (size_t)b * NC_ * D_;
  const float* alp = alphav + b * NC_;
  const float* bet = betav + b * NC_;
  unsigned short* Pb = P + (size_t)b * LQ_ * NC_;

  __shared__ short As[CBM * 72];   // padded (64+8) to break read bank conflicts
  __shared__ short Bs[CBN * CBK];  // linear: required by global_load_lds

  int t = threadIdx.x, lane = t & 63, wid = t >> 6;
  int wm = wid >> 1, wn = wid & 1;
  f4 acc[4][5] = {};

  for (int k0 = 0; k0 < D_; k0 += CBK) {
    __syncthreads();
    // B via async global->LDS (16B/lane)
    for (int i = wid; i < 20; i += 4) {
      const unsigned short* src = Bb + (size_t)(n0 + i * 8 + (lane >> 3)) * D_ + k0 + (lane & 7) * 8;
      gload16(src, (char*)Bs + i * 1024);
    }
    // A: reg-stage fp32 -> bf16
#pragma unroll
    for (int p = 0; p < 4; ++p) {
      int row = p * 32 + (t >> 3);
      int kc = (t & 7) * 8;
      const float* src = Ab + (size_t)(m0 + row) * D_ + k0 + kc;
      f4 v0 = *(const f4*)src;
      f4 v1 = *(const f4*)(src + 4);
      us8 u;
#pragma unroll
      for (int j = 0; j < 4; ++j) { u[j] = f2bf(v0[j]); u[4 + j] = f2bf(v1[j]); }
      *(us8*)(As + row * 72 + kc) = u;
    }
    __syncthreads();
#pragma unroll
    for (int kk = 0; kk < 2; ++kk) {
      short8 fa[4], fb[5];
#pragma unroll
      for (int mi = 0; mi < 4; ++mi)
        fa[mi] = *(const short8*)(As + (wm * 64 + mi * 16 + (lane & 15)) * 72 + kk * 32 + (lane >> 4) * 8);
#pragma unroll
      for (int ni = 0; ni < 5; ++ni)
        fb[ni] = *(const short8*)(Bs + (wn * 80 + ni * 16 + (lane & 15)) * 64 + kk * 32 + (lane >> 4) * 8);
#pragma unroll
      for (int mi = 0; mi < 4; ++mi)
#pragma unroll
        for (int ni = 0; ni < 5; ++ni)
          acc[mi][ni] = __builtin_amdgcn_mfma_f32_16x16x32_bf16(fa[mi], fb[ni], acc[mi][ni], 0, 0, 0);
    }
  }
  // epilogue: score' = alpha*score + beta; per-head (80-col, one wave) softmax
  float al[5], be[5];
#pragma unroll
  for (int ni = 0; ni < 5; ++ni) {
    int c = n0 + wn * 80 + ni * 16 + (lane & 15);
    al[ni] = alp[c]; be[ni] = bet[c];
  }
#pragma unroll
  for (int mi = 0; mi < 4; ++mi) {
#pragma unroll
    for (int j = 0; j < 4; ++j) {
      float v[5];
      float m = -3.0e38f;
#pragma unroll
      for (int ni = 0; ni < 5; ++ni) { v[ni] = acc[mi][ni][j] * al[ni] + be[ni]; m = fmaxf(m, v[ni]); }
#pragma unroll
      for (int off = 1; off < 16; off <<= 1) m = fmaxf(m, __shfl_xor(m, off, 64));
      float ssum = 0.f;
#pragma unroll
      for (int ni = 0; ni < 5; ++ni) { v[ni] = __expf(v[ni] - m); ssum += v[ni]; }
#pragma unroll
      for (int off = 1; off < 16; off <<= 1) ssum += __shfl_xor(ssum, off, 64);
      float inv = 1.f / ssum;
      int row = m0 + wm * 64 + mi * 16 + (lane >> 4) * 4 + j;
      size_t rb = (size_t)row * NC_ + n0 + wn * 80 + (lane & 15);
#pragma unroll
      for (int ni = 0; ni < 5; ++ni)
        Pb[rb + ni * 16] = f2bf(v[ni] * inv);
    }
  }
}

// ---------------- D: out = P @ Ut^T + bo ----------------
#define DBM 128
#define DBN 128
#define DBK 64
__global__ __launch_bounds__(256) void k_out(
    const unsigned short* __restrict__ P, const unsigned short* __restrict__ Ut,
    const float* __restrict__ bo, float* __restrict__ out) {
  int id = blockIdx.x;
  int x = id & 7, idp = id >> 3;
  int n_t = idp & 7;
  int pid = (idp >> 3) * 8 + x;
  int b = pid >> 5, m_t = pid & 31;
  int m0 = m_t * DBM, n0 = n_t * DBN;

  const unsigned short* Ab = P + (size_t)b * LQ_ * NC_;
  const unsigned short* Bb = Ut + (size_t)b * D_ * NC_;
  float* ob = out + (size_t)b * LQ_ * D_;

  __shared__ short As[DBM * DBK];
  __shared__ short Bs[DBN * DBK];
  int t = threadIdx.x, lane = t & 63, wid = t >> 6;
  int wm = wid >> 1, wn = wid & 1;
  f4 acc[4][4] = {};

  for (int k0 = 0; k0 < NC_; k0 += DBK) {
    __syncthreads();
    for (int i = wid; i < 32; i += 4) {
      if (i < 16) {
        const unsigned short* src = Ab + (size_t)(m0 + i * 8 + (lane >> 3)) * NC_ + k0 + (lane & 7) * 8;
        gload16(src, (char*)As + i * 1024);
      } else {
        int i2 = i - 16;
        const unsigned short* src = Bb + (size_t)(n0 + i2 * 8 + (lane >> 3)) * NC_ + k0 + (lane & 7) * 8;
        gload16(src, (char*)Bs + i2 * 1024);
      }
    }
    __syncthreads();
#pragma unroll
    for (int kk = 0; kk < 2; ++kk) {
      short8 fa[4], fb[4];
#pragma unroll
      for (int mi = 0; mi < 4; ++mi)
        fa[mi] = *(const short8*)(As + (wm * 64 + mi * 16 + (lane & 15)) * 64 + kk * 32 + (lane >> 4) * 8);
#pragma unroll
      for (int ni = 0; ni < 4; ++ni)
        fb[ni] = *(const short8*)(Bs + (wn * 64 + ni * 16 + (lane & 15)) * 64 + kk * 32 + (lane >> 4) * 8);
#pragma unroll
      for (int mi = 0; mi < 4; ++mi)
#pragma unroll
        for (int ni = 0; ni < 4; ++ni)
          acc[mi][ni] = __builtin_amdgcn_mfma_f32_16x16x32_bf16(fa[mi], fb[ni], acc[mi][ni], 0, 0, 0);
    }
  }
#pragma unroll
  for (int ni = 0; ni < 4; ++ni) {
    int col = n0 + wn * 64 + ni * 16 + (lane & 15);
    float bov = bo[col];
#pragma unroll
    for (int mi = 0; mi < 4; ++mi)
#pragma unroll
      for (int j = 0; j < 4; ++j) {
        int row = m0 + wm * 64 + mi * 16 + (lane >> 4) * 4 + j;
        ob[(size_t)row * D_ + col] = acc[mi][ni][j] + bov;
      }
  }
}

extern "C" void kernel_launch(void* const* d_in, const int* in_sizes, int n_in,
                              void* d_out, int out_size, void* d_ws, size_t ws_size,
                              hipStream_t stream) {
  const float* hs  = (const float*)d_in[0];
  const float* ehs = (const float*)d_in[1];
  const float* Wq  = (const float*)d_in[2];
  const float* Wk  = (const float*)d_in[3];
  const float* Wv  = (const float*)d_in[4];
  const float* Wo  = (const float*)d_in[5];
  const float* bo  = (const float*)d_in[6];
  const float* Ak  = (const float*)d_in[7];
  const float* Bk  = (const float*)d_in[8];
  const float* Av  = (const float*)d_in[9];
  const float* Bv  = (const float*)d_in[10];
  const float* Ao  = (const float*)d_in[11];
  const float* Bo  = (const float*)d_in[12];
  const float* csf = (const float*)d_in[13];
  const int*   sb  = (const int*)d_in[14];
  const int*   sn  = (const int*)d_in[15];
  float* out = (float*)d_out;

  char* ws = (char*)d_ws;
  unsigned short* P    = (unsigned short*)(ws);              // 83,886,080
  unsigned short* Mt   = (unsigned short*)(ws + 83886080);   // 20,971,520
  unsigned short* Ut   = (unsigned short*)(ws + 104857600);  // 20,971,520
  float* kbuf   = (float*)(ws + 125829120);                  //  2,621,440
  float* vbuf   = (float*)(ws + 128450560);                  //  2,621,440
  float* weff   = (float*)(ws + 131072000);                  // 12,582,912
  float* wqT    = (float*)(ws + 143654912);                  //  4,194,304
  float* aT     = (float*)(ws + 147849216);                  //  2,359,296
  float* hssum  = (float*)(ws + 150208512);                  //     32,768
  float* qmean  = (float*)(ws + 150241280);                  //     32,768
  float* alphav = (float*)(ws + 150274048);                  //     40,960
  float* betav  = (float*)(ws + 150315008);                  //     40,960

  float* wkE = weff;
  float* wvE = weff + 1048576;
  float* woE = weff + 2097152;
  float* akT = aT;
  float* avT = aT + 196608;
  float* aoT = aT + 393216;

  const float LS = 16.0f / 192.0f;

  hipMemsetAsync(hssum, 0, B_ * D_ * sizeof(float), stream);
  k_hssum<<<dim3(64, 8), 256, 0, stream>>>(hs, hssum);

  // transposes: Wq^T, Ak^T, Av^T, Ao^T
  k_tr<<<dim3(32, 32), 256, 0, stream>>>(Wq, wqT, 1024, 1024);
  k_tr<<<dim3(32, 6), 256, 0, stream>>>(Ak, akT, 192, 1024);
  k_tr<<<dim3(32, 6), 256, 0, stream>>>(Av, avT, 192, 1024);
  k_tr<<<dim3(32, 6), 256, 0, stream>>>(Ao, aoT, 192, 1024);

  // W_eff = W + (1/12) Bx@Ax
  k_gemm_small<false><<<dim3(16, 16, 1), 256, 0, stream>>>(
      Bk, 192, 0, 0, akT, 192, 0, 0, wkE, 1024, 0, 0, Wk, 1024,
      1024, 1024, 1024, 192, LS, 1);
  k_gemm_small<false><<<dim3(16, 16, 1), 256, 0, stream>>>(
      Bv, 192, 0, 0, avT, 192, 0, 0, wvE, 1024, 0, 0, Wv, 1024,
      1024, 1024, 1024, 192, LS, 1);
  k_gemm_small<false><<<dim3(16, 16, 1), 256, 0, stream>>>(
      Bo, 192, 0, 0, aoT, 192, 0, 0, woE, 1024, 0, 0, Wo, 1024,
      1024, 1024, 1024, 192, LS, 1);

  // k,v = ehs @ W_eff^T  (80 rows stored/b, rows 77..79 zeroed via Mv guard)
  k_gemm_small<false><<<dim3(2, 16, 8), 256, 0, stream>>>(
      ehs, 1024, 77L * 1024, 0, wkE, 1024, 0, 0, kbuf, 1024, 80L * 1024, 0, nullptr, 0,
      80, 77, 1024, 1024, 1.f, 1);
  k_gemm_small<false><<<dim3(2, 16, 8), 256, 0, stream>>>(
      ehs, 1024, 77L * 1024, 0, wvE, 1024, 0, 0, vbuf, 1024, 80L * 1024, 0, nullptr, 0,
      80, 77, 1024, 1024, 1.f, 1);

  // qmean = (1/4096) hssum @ Wq^T
  k_gemm_small<false><<<dim3(1, 16, 1), 256, 0, stream>>>(
      hssum, 1024, 0, 0, Wq, 1024, 0, 0, qmean, 1024, 0, 0, nullptr, 0,
      8, 8, 1024, 1024, 1.f / 4096.f, 1);

  // Mt[b,h] = 0.125 * k_bh @ Wq_h   (bf16, [b][h*80+s][d])
  k_gemm_small<true><<<dim3(2, 16, 128), 256, 0, stream>>>(
      kbuf, 1024, 80L * 1024, 64L, wqT, 1024, 0, 64L,
      Mt, 1024, (long)NC_ * 1024, 80L * 1024, nullptr, 0,
      80, 80, 1024, 64, 0.125f, 16);

  // Ut[b,h] = Wo_eff_h @ v_bh^T   (bf16, [b][e][h*80+s])
  k_gemm_small<true><<<dim3(16, 2, 128), 256, 0, stream>>>(
      woE, 1024, 0, 64L, vbuf, 1024, 80L * 1024, 64L,
      Ut, NC_, 1024L * NC_, 80L, nullptr, 0,
      1024, 1024, 80, 64, 1.f, 16);

  // per-(b,h,s) column mean + subject alpha/beta
  k_mubeta<<<dim3(16, 8), 128, 0, stream>>>(qmean, kbuf, sb, sn, csf, alphav, betav);

  // big fused GEMMs
  k_score<<<2048, 256, 0, stream>>>(hs, Mt, alphav, betav, P);
  k_out<<<2048, 256, 0, stream>>>(P, Ut, bo, out);

  (void)in_sizes; (void)n_in; (void)out_size; (void)ws_size;
}

// Round 2
// 490.178 us; speedup vs baseline: 1.0815x; 1.0815x over previous
//
#include <hip/hip_runtime.h>
#include <stdint.h>

#define B_     8
#define LQ_    4096
#define S_     77
#define SP_    80
#define D_     1024
#define H_     16
#define HD_    64
#define NC_    1280   // H_*SP_
#define NSUBJ_ 32

typedef __attribute__((ext_vector_type(4))) float  f4;
typedef __attribute__((ext_vector_type(8))) short  short8;
typedef __attribute__((ext_vector_type(8))) unsigned short us8;
typedef __attribute__((ext_vector_type(4))) unsigned short us4;

__device__ __forceinline__ unsigned short f2bf(float f) {
  union { float f; unsigned u; } x; x.f = f;
  unsigned r = x.u + 0x7FFFu + ((x.u >> 16) & 1u);
  return (unsigned short)(r >> 16);
}

__device__ __forceinline__ void gload16(const void* g, void* s) {
  __builtin_amdgcn_global_load_lds((const __attribute__((address_space(1))) void*)g,
                                   (__attribute__((address_space(3))) void*)s, 16, 0, 0);
}

// ---------------- hssum partials + hs -> bf16 convert ----------------
__global__ __launch_bounds__(256) void k_hssum(const float* __restrict__ hs,
                                               float* __restrict__ part,
                                               unsigned short* __restrict__ hsb) {
  int b = blockIdx.y;
  size_t base = ((size_t)b * LQ_ + (size_t)blockIdx.x * 64) * D_ + threadIdx.x * 4;
  f4 acc = {0.f, 0.f, 0.f, 0.f};
  for (int l = 0; l < 64; ++l) {
    f4 v = *(const f4*)(hs + base + (size_t)l * D_);
    acc += v;
    if (hsb) {
      us4 o;
#pragma unroll
      for (int j = 0; j < 4; ++j) o[j] = f2bf(v[j]);
      *(us4*)(hsb + base + (size_t)l * D_) = o;
    }
  }
  *(f4*)(part + (size_t)blockIdx.x * (B_ * D_) + b * D_ + threadIdx.x * 4) = acc;
}

__global__ __launch_bounds__(256) void k_hsred(const float* __restrict__ part,
                                               float* __restrict__ hssum) {
  int i = blockIdx.x * 256 + threadIdx.x;   // [0, 8192)
  float s = 0.f;
  for (int x = 0; x < 64; ++x) s += part[(size_t)x * (B_ * D_) + i];
  hssum[i] = s;
}

// ---------------- transpose fp32 (R,C)->(C,R), dims %32==0 ----------------
__global__ __launch_bounds__(256) void k_tr(const float* __restrict__ in,
                                            float* __restrict__ out, int R, int C) {
  __shared__ float tile[32][33];
  int c0 = blockIdx.x * 32, r0 = blockIdx.y * 32;
  int tx = threadIdx.x & 31, ty = threadIdx.x >> 5;
#pragma unroll
  for (int k = 0; k < 4; ++k)
    tile[ty + 8 * k][tx] = in[(size_t)(r0 + ty + 8 * k) * C + c0 + tx];
  __syncthreads();
#pragma unroll
  for (int k = 0; k < 4; ++k)
    out[(size_t)(c0 + ty + 8 * k) * R + r0 + tx] = tile[tx][ty + 8 * k];
}

// ---------------- generic small GEMM: C = alpha*(A @ Bt^T) [+ Dm], bf16 MFMA ----------------
template <bool OBF>
__global__ __launch_bounds__(256) void k_gemm_small(
    const float* __restrict__ A, int lda, long sA1, long sA2,
    const float* __restrict__ Bt, int ldb, long sB1, long sB2,
    void* __restrict__ Cv, int ldc, long sC1, long sC2,
    const float* __restrict__ Dm, int ldd,
    int M, int Mv, int N, int K, float alpha, int Z2) {
  int z = blockIdx.z, z1 = z / Z2, z2 = z - z1 * Z2;
  A  += z1 * sA1 + z2 * sA2;
  Bt += z1 * sB1 + z2 * sB2;
  long cbase = z1 * sC1 + z2 * sC2;
  __shared__ short As[64 * 40];
  __shared__ short Bs[64 * 40];
  int t = threadIdx.x, lane = t & 63, wid = t >> 6;
  int wm = wid >> 1, wn = wid & 1;
  int m0 = blockIdx.x * 64, n0 = blockIdx.y * 64;
  f4 acc[2][2] = {};
  int srow = t >> 2, skc = (t & 3) * 8;
  for (int k0 = 0; k0 < K; k0 += 32) {
    __syncthreads();
    f4 a0 = {0,0,0,0}, a1 = {0,0,0,0}, b0 = {0,0,0,0}, b1 = {0,0,0,0};
    if (m0 + srow < Mv) {
      const float* p = A + (size_t)(m0 + srow) * lda + k0 + skc;
      a0 = *(const f4*)p; a1 = *(const f4*)(p + 4);
    }
    if (n0 + srow < N) {
      const float* p = Bt + (size_t)(n0 + srow) * ldb + k0 + skc;
      b0 = *(const f4*)p; b1 = *(const f4*)(p + 4);
    }
    us8 ua, ub;
#pragma unroll
    for (int j = 0; j < 4; ++j) {
      ua[j] = f2bf(a0[j]); ua[4 + j] = f2bf(a1[j]);
      ub[j] = f2bf(b0[j]); ub[4 + j] = f2bf(b1[j]);
    }
    *(us8*)(As + srow * 40 + skc) = ua;
    *(us8*)(Bs + srow * 40 + skc) = ub;
    __syncthreads();
    short8 fa[2], fb[2];
#pragma unroll
    for (int i = 0; i < 2; ++i) {
      fa[i] = *(const short8*)(As + (wm * 32 + i * 16 + (lane & 15)) * 40 + (lane >> 4) * 8);
      fb[i] = *(const short8*)(Bs + (wn * 32 + i * 16 + (lane & 15)) * 40 + (lane >> 4) * 8);
    }
#pragma unroll
    for (int mi = 0; mi < 2; ++mi)
#pragma unroll
      for (int ni = 0; ni < 2; ++ni)
        acc[mi][ni] = __builtin_amdgcn_mfma_f32_16x16x32_bf16(fa[mi], fb[ni], acc[mi][ni], 0, 0, 0);
  }
#pragma unroll
  for (int mi = 0; mi < 2; ++mi)
#pragma unroll
    for (int ni = 0; ni < 2; ++ni)
#pragma unroll
      for (int j = 0; j < 4; ++j) {
        int row = m0 + wm * 32 + mi * 16 + (lane >> 4) * 4 + j;
        int col = n0 + wn * 32 + ni * 16 + (lane & 15);
        if (row < M && col < N) {
          float val = acc[mi][ni][j] * alpha;
          if (Dm) val += Dm[(size_t)row * ldd + col];
          size_t idx = (size_t)cbase + (size_t)row * ldc + col;
          if (OBF) ((unsigned short*)Cv)[idx] = f2bf(val);
          else     ((float*)Cv)[idx] = val;
        }
      }
}

// ---------------- mu/alpha/beta per (b,h,s) ----------------
__global__ void k_mubeta(const float* __restrict__ qmean, const float* __restrict__ kbuf,
                         const int* __restrict__ sb, const int* __restrict__ sn,
                         const float* __restrict__ csf_p,
                         float* __restrict__ alphav, float* __restrict__ betav) {
  int h = blockIdx.x, b = blockIdx.y, s = threadIdx.x;
  if (s >= SP_) return;
  const float* qp = qmean + b * D_ + h * HD_;
  const float* kp = kbuf + ((size_t)(b * SP_ + s)) * D_ + h * HD_;
  float mu = 0.f;
#pragma unroll 8
  for (int hd = 0; hd < HD_; ++hd) mu += qp[hd] * kp[hd];
  mu *= 0.125f;
  bool subj = false;
  for (int i = 0; i < NSUBJ_; ++i) subj = subj || (sb[i] == b && sn[i] == s);
  float csf = *csf_p;
  int c = b * NC_ + h * SP_ + s;
  alphav[c] = subj ? csf : 1.f;
  betav[c] = (s >= S_) ? -1e30f : (subj ? -mu * csf : 0.f);
}

// ---------------- C: score GEMM + per-head softmax -> P bf16 ----------------
// XOR chunk swizzle (T2 / rule 21): LDS rows are linear 64 shorts (8 chunks of
// 16B); LDS[row][c'] holds global chunk c'^(row&7). gload_lds sources are
// pre-swizzled per-lane; reads XOR the chunk index. Read conflicts drop from
// ~16-way to the 8-way b128 floor.
#define CBM 128
#define CBN 160
template <bool AHSB>
__global__ __launch_bounds__(256) void k_score(
    const void* __restrict__ Aany, const unsigned short* __restrict__ Mt,
    const float* __restrict__ alphav, const float* __restrict__ betav,
    unsigned short* __restrict__ P) {
  int id = blockIdx.x;
  int x = id & 7, idp = id >> 3;
  int n_t = idp & 7;
  int pid = (idp >> 3) * 8 + x;     // [0,256): XCDs sweep n_t for a fixed (b,m)-panel
  int b = pid >> 5, m_t = pid & 31;
  int m0 = m_t * CBM, n0 = n_t * CBN;

  const unsigned short* Abf = (const unsigned short*)Aany + (size_t)b * LQ_ * D_;
  const float*          Af  = (const float*)Aany + (size_t)b * LQ_ * D_;
  const unsigned short* Bb  = Mt + (size_t)b * NC_ * D_;
  const float* alp = alphav + b * NC_;
  const float* bet = betav + b * NC_;
  unsigned short* Pb = P + (size_t)b * LQ_ * NC_;

  __shared__ short As[CBM * 64];
  __shared__ short Bs[CBN * 64];

  int t = threadIdx.x, lane = t & 63, wid = t >> 6;
  int wm = wid >> 1, wn = wid & 1;
  int srow = lane >> 3;                         // 0..7 within an 8-row group
  int schunk = (lane & 7) ^ srow;               // pre-swizzled source chunk
  f4 acc[4][5] = {};

  for (int k0 = 0; k0 < D_; k0 += 64) {
    __syncthreads();
    // B: 160 rows via global_load_lds, swizzled source
    for (int i = wid; i < 20; i += 4) {
      const unsigned short* src = Bb + (size_t)(n0 + i * 8 + srow) * D_ + k0 + schunk * 8;
      gload16(src, (char*)Bs + i * 1024);
    }
    if (AHSB) {
      // A: bf16 via global_load_lds, swizzled source
      for (int i = wid; i < 16; i += 4) {
        const unsigned short* src = Abf + (size_t)(m0 + i * 8 + srow) * D_ + k0 + schunk * 8;
        gload16(src, (char*)As + i * 1024);
      }
    } else {
      // A: reg-stage fp32 -> bf16, swizzled ds_write
      int arow = t >> 3, ac = t & 7;
      int awc = ac ^ (arow & 7);
#pragma unroll
      for (int p = 0; p < 4; ++p) {
        int row = p * 32 + arow;
        const float* src = Af + (size_t)(m0 + row) * D_ + k0 + ac * 8;
        f4 v0 = *(const f4*)src;
        f4 v1 = *(const f4*)(src + 4);
        us8 u;
#pragma unroll
        for (int j = 0; j < 4; ++j) { u[j] = f2bf(v0[j]); u[4 + j] = f2bf(v1[j]); }
        *(us8*)(As + row * 64 + awc * 8) = u;
      }
    }
    __syncthreads();
#pragma unroll
    for (int kk = 0; kk < 2; ++kk) {
      int co = ((kk * 4 + (lane >> 4)) ^ (lane & 7)) * 8;   // swizzled read chunk
      short8 fa[4], fb[5];
#pragma unroll
      for (int mi = 0; mi < 4; ++mi)
        fa[mi] = *(const short8*)(As + (wm * 64 + mi * 16 + (lane & 15)) * 64 + co);
#pragma unroll
      for (int ni = 0; ni < 5; ++ni)
        fb[ni] = *(const short8*)(Bs + (wn * 80 + ni * 16 + (lane & 15)) * 64 + co);
#pragma unroll
      for (int mi = 0; mi < 4; ++mi)
#pragma unroll
        for (int ni = 0; ni < 5; ++ni)
          acc[mi][ni] = __builtin_amdgcn_mfma_f32_16x16x32_bf16(fa[mi], fb[ni], acc[mi][ni], 0, 0, 0);
    }
  }
  // epilogue: score' = alpha*score + beta; per-head (80-col) softmax in one wave
  float al[5], be[5];
#pragma unroll
  for (int ni = 0; ni < 5; ++ni) {
    int c = n0 + wn * 80 + ni * 16 + (lane & 15);
    al[ni] = alp[c]; be[ni] = bet[c];
  }
#pragma unroll
  for (int mi = 0; mi < 4; ++mi) {
#pragma unroll
    for (int j = 0; j < 4; ++j) {
      float v[5];
      float m = -3.0e38f;
#pragma unroll
      for (int ni = 0; ni < 5; ++ni) { v[ni] = acc[mi][ni][j] * al[ni] + be[ni]; m = fmaxf(m, v[ni]); }
#pragma unroll
      for (int off = 1; off < 16; off <<= 1) m = fmaxf(m, __shfl_xor(m, off, 64));
      float ssum = 0.f;
#pragma unroll
      for (int ni = 0; ni < 5; ++ni) { v[ni] = __expf(v[ni] - m); ssum += v[ni]; }
#pragma unroll
      for (int off = 1; off < 16; off <<= 1) ssum += __shfl_xor(ssum, off, 64);
      float inv = 1.f / ssum;
      int row = m0 + wm * 64 + mi * 16 + (lane >> 4) * 4 + j;
      size_t rb = (size_t)row * NC_ + n0 + wn * 80 + (lane & 15);
#pragma unroll
      for (int ni = 0; ni < 5; ++ni)
        Pb[rb + ni * 16] = f2bf(v[ni] * inv);
    }
  }
}

// ---------------- D: out = P @ Ut^T + bo ----------------
#define DBM 128
#define DBN 128
__global__ __launch_bounds__(256) void k_out(
    const unsigned short* __restrict__ P, const unsigned short* __restrict__ Ut,
    const float* __restrict__ bo, float* __restrict__ out) {
  int id = blockIdx.x;
  int x = id & 7, idp = id >> 3;
  int n_t = idp & 7;
  int pid = (idp >> 3) * 8 + x;
  int b = pid >> 5, m_t = pid & 31;
  int m0 = m_t * DBM, n0 = n_t * DBN;

  const unsigned short* Ab = P + (size_t)b * LQ_ * NC_;
  const unsigned short* Bb = Ut + (size_t)b * D_ * NC_;
  float* ob = out + (size_t)b * LQ_ * D_;

  __shared__ short As[DBM * 64];
  __shared__ short Bs[DBN * 64];
  int t = threadIdx.x, lane = t & 63, wid = t >> 6;
  int wm = wid >> 1, wn = wid & 1;
  int srow = lane >> 3;
  int schunk = (lane & 7) ^ srow;
  f4 acc[4][4] = {};

  for (int k0 = 0; k0 < NC_; k0 += 64) {
    __syncthreads();
    for (int i = wid; i < 32; i += 4) {
      if (i < 16) {
        const unsigned short* src = Ab + (size_t)(m0 + i * 8 + srow) * NC_ + k0 + schunk * 8;
        gload16(src, (char*)As + i * 1024);
      } else {
        int i2 = i - 16;
        const unsigned short* src = Bb + (size_t)(n0 + i2 * 8 + srow) * NC_ + k0 + schunk * 8;
        gload16(src, (char*)Bs + i2 * 1024);
      }
    }
    __syncthreads();
#pragma unroll
    for (int kk = 0; kk < 2; ++kk) {
      int co = ((kk * 4 + (lane >> 4)) ^ (lane & 7)) * 8;
      short8 fa[4], fb[4];
#pragma unroll
      for (int mi = 0; mi < 4; ++mi)
        fa[mi] = *(const short8*)(As + (wm * 64 + mi * 16 + (lane & 15)) * 64 + co);
#pragma unroll
      for (int ni = 0; ni < 4; ++ni)
        fb[ni] = *(const short8*)(Bs + (wn * 64 + ni * 16 + (lane & 15)) * 64 + co);
#pragma unroll
      for (int mi = 0; mi < 4; ++mi)
#pragma unroll
        for (int ni = 0; ni < 4; ++ni)
          acc[mi][ni] = __builtin_amdgcn_mfma_f32_16x16x32_bf16(fa[mi], fb[ni], acc[mi][ni], 0, 0, 0);
    }
  }
#pragma unroll
  for (int ni = 0; ni < 4; ++ni) {
    int col = n0 + wn * 64 + ni * 16 + (lane & 15);
    float bov = bo[col];
#pragma unroll
    for (int mi = 0; mi < 4; ++mi)
#pragma unroll
      for (int j = 0; j < 4; ++j) {
        int row = m0 + wm * 64 + mi * 16 + (lane >> 4) * 4 + j;
        ob[(size_t)row * D_ + col] = acc[mi][ni][j] + bov;
      }
  }
}

extern "C" void kernel_launch(void* const* d_in, const int* in_sizes, int n_in,
                              void* d_out, int out_size, void* d_ws, size_t ws_size,
                              hipStream_t stream) {
  const float* hs  = (const float*)d_in[0];
  const float* ehs = (const float*)d_in[1];
  const float* Wq  = (const float*)d_in[2];
  const float* Wk  = (const float*)d_in[3];
  const float* Wv  = (const float*)d_in[4];
  const float* Wo  = (const float*)d_in[5];
  const float* bo  = (const float*)d_in[6];
  const float* Ak  = (const float*)d_in[7];
  const float* Bk  = (const float*)d_in[8];
  const float* Av  = (const float*)d_in[9];
  const float* Bv  = (const float*)d_in[10];
  const float* Ao  = (const float*)d_in[11];
  const float* Bo  = (const float*)d_in[12];
  const float* csf = (const float*)d_in[13];
  const int*   sb  = (const int*)d_in[14];
  const int*   sn  = (const int*)d_in[15];
  float* out = (float*)d_out;

  char* ws = (char*)d_ws;
  // persistent across the big GEMMs:
  unsigned short* P  = (unsigned short*)ws;                   // 83,886,080
  unsigned short* Mt = (unsigned short*)(ws + 83886080);      // 20,971,520
  unsigned short* Ut = (unsigned short*)(ws + 104857600);     // 20,971,520
  const size_t NEED_HSB = 125829120ULL + 67108864ULL + 81920ULL; // 193,019,904
  bool useHsb = ws_size >= NEED_HSB;
  unsigned short* hsb = useHsb ? (unsigned short*)(ws + 125829120) : nullptr;
  char* tail = useHsb ? (ws + 192937984) : (ws + 125829120);
  float* alphav = (float*)tail;
  float* betav  = (float*)(tail + 40960);
  // temporaries overlapped into P's region (all dead before k_score writes P):
  float* kbuf  = (float*)(ws + 0);            //  2,621,440
  float* vbuf  = (float*)(ws + 2621440);      //  2,621,440
  float* weff  = (float*)(ws + 5242880);      // 12,582,912
  float* wqT   = (float*)(ws + 17825792);     //  4,194,304
  float* aT    = (float*)(ws + 22020096);     //  2,359,296
  float* part  = (float*)(ws + 24379392);     //  2,097,152
  float* hssum = (float*)(ws + 26476544);     //     32,768
  float* qmean = (float*)(ws + 26509312);     //     32,768

  float* wkE = weff;
  float* wvE = weff + 1048576;
  float* woE = weff + 2097152;
  float* akT = aT;
  float* avT = aT + 196608;
  float* aoT = aT + 393216;

  const float LS = 16.0f / 192.0f;

  // hs row-sums (deterministic two-stage) + bf16 conversion of hs
  k_hssum<<<dim3(64, 8), 256, 0, stream>>>(hs, part, hsb);
  k_hsred<<<32, 256, 0, stream>>>(part, hssum);

  // transposes: Wq^T, Ak^T, Av^T, Ao^T
  k_tr<<<dim3(32, 32), 256, 0, stream>>>(Wq, wqT, 1024, 1024);
  k_tr<<<dim3(32, 6), 256, 0, stream>>>(Ak, akT, 192, 1024);
  k_tr<<<dim3(32, 6), 256, 0, stream>>>(Av, avT, 192, 1024);
  k_tr<<<dim3(32, 6), 256, 0, stream>>>(Ao, aoT, 192, 1024);

  // W_eff = W + (1/12) Bx@Ax
  k_gemm_small<false><<<dim3(16, 16, 1), 256, 0, stream>>>(
      Bk, 192, 0, 0, akT, 192, 0, 0, wkE, 1024, 0, 0, Wk, 1024,
      1024, 1024, 1024, 192, LS, 1);
  k_gemm_small<false><<<dim3(16, 16, 1), 256, 0, stream>>>(
      Bv, 192, 0, 0, avT, 192, 0, 0, wvE, 1024, 0, 0, Wv, 1024,
      1024, 1024, 1024, 192, LS, 1);
  k_gemm_small<false><<<dim3(16, 16, 1), 256, 0, stream>>>(
      Bo, 192, 0, 0, aoT, 192, 0, 0, woE, 1024, 0, 0, Wo, 1024,
      1024, 1024, 1024, 192, LS, 1);

  // k,v = ehs @ W_eff^T  (80 rows/b, rows 77..79 written as zeros)
  k_gemm_small<false><<<dim3(2, 16, 8), 256, 0, stream>>>(
      ehs, 1024, 77L * 1024, 0, wkE, 1024, 0, 0, kbuf, 1024, 80L * 1024, 0, nullptr, 0,
      80, 77, 1024, 1024, 1.f, 1);
  k_gemm_small<false><<<dim3(2, 16, 8), 256, 0, stream>>>(
      ehs, 1024, 77L * 1024, 0, wvE, 1024, 0, 0, vbuf, 1024, 80L * 1024, 0, nullptr, 0,
      80, 77, 1024, 1024, 1.f, 1);

  // qmean = (1/4096) hssum @ Wq^T
  k_gemm_small<false><<<dim3(1, 16, 1), 256, 0, stream>>>(
      hssum, 1024, 0, 0, Wq, 1024, 0, 0, qmean, 1024, 0, 0, nullptr, 0,
      8, 8, 1024, 1024, 1.f / 4096.f, 1);

  // Mt[b,h] = 0.125 * k_bh @ Wq_h   (bf16, [b][h*80+s][d])
  k_gemm_small<true><<<dim3(2, 16, 128), 256, 0, stream>>>(
      kbuf, 1024, 80L * 1024, 64L, wqT, 1024, 0, 64L,
      Mt, 1024, (long)NC_ * 1024, 80L * 1024, nullptr, 0,
      80, 80, 1024, 64, 0.125f, 16);

  // Ut[b,h] = Wo_eff_h @ v_bh^T   (bf16, [b][e][h*80+s])
  k_gemm_small<true><<<dim3(16, 2, 128), 256, 0, stream>>>(
      woE, 1024, 0, 64L, vbuf, 1024, 80L * 1024, 64L,
      Ut, NC_, 1024L * NC_, 80L, nullptr, 0,
      1024, 1024, 80, 64, 1.f, 16);

  // per-(b,h,s) column mean + subject alpha/beta
  k_mubeta<<<dim3(16, 8), 128, 0, stream>>>(qmean, kbuf, sb, sn, csf, alphav, betav);

  // big fused GEMMs
  if (useHsb)
    k_score<true><<<2048, 256, 0, stream>>>(hsb, Mt, alphav, betav, P);
  else
    k_score<false><<<2048, 256, 0, stream>>>(hs, Mt, alphav, betav, P);
  k_out<<<2048, 256, 0, stream>>>(P, Ut, bo, out);

  (void)in_sizes; (void)n_in; (void)out_size; (void)ws_size;
}

// Round 3
// 428.893 us; speedup vs baseline: 1.2360x; 1.1429x over previous
//
#include <hip/hip_runtime.h>
#include <stdint.h>

#define B_     8
#define LQ_    4096
#define S_     77
#define SP_    80
#define D_     1024
#define H_     16
#define HD_    64
#define NC_    1280   // H_*SP_
#define NSUBJ_ 32

typedef __attribute__((ext_vector_type(4))) float  f4;
typedef __attribute__((ext_vector_type(8))) short  short8;
typedef __attribute__((ext_vector_type(8))) unsigned short us8;
typedef __attribute__((ext_vector_type(4))) unsigned short us4;

__device__ __forceinline__ unsigned short f2bf(float f) {
  union { float f; unsigned u; } x; x.f = f;
  unsigned r = x.u + 0x7FFFu + ((x.u >> 16) & 1u);
  return (unsigned short)(r >> 16);
}

__device__ __forceinline__ void gload16(const void* g, void* s) {
  __builtin_amdgcn_global_load_lds((const __attribute__((address_space(1))) void*)g,
                                   (__attribute__((address_space(3))) void*)s, 16, 0, 0);
}

// ---------------- hssum partials + hs -> bf16 convert ----------------
__global__ __launch_bounds__(256) void k_hssum(const float* __restrict__ hs,
                                               float* __restrict__ part,
                                               unsigned short* __restrict__ hsb) {
  int b = blockIdx.y;
  size_t base = ((size_t)b * LQ_ + (size_t)blockIdx.x * 64) * D_ + threadIdx.x * 4;
  f4 acc = {0.f, 0.f, 0.f, 0.f};
  for (int l = 0; l < 64; ++l) {
    f4 v = *(const f4*)(hs + base + (size_t)l * D_);
    acc += v;
    if (hsb) {
      us4 o;
#pragma unroll
      for (int j = 0; j < 4; ++j) o[j] = f2bf(v[j]);
      *(us4*)(hsb + base + (size_t)l * D_) = o;
    }
  }
  *(f4*)(part + (size_t)blockIdx.x * (B_ * D_) + b * D_ + threadIdx.x * 4) = acc;
}

__global__ __launch_bounds__(256) void k_hsred(const float* __restrict__ part,
                                               float* __restrict__ hssum) {
  int i = blockIdx.x * 256 + threadIdx.x;   // [0, 8192)
  float s = 0.f;
  for (int x = 0; x < 64; ++x) s += part[(size_t)x * (B_ * D_) + i];
  hssum[i] = s;
}

// ---------------- transpose fp32 (R,C)->(C,R), dims %32==0 ----------------
__global__ __launch_bounds__(256) void k_tr(const float* __restrict__ in,
                                            float* __restrict__ out, int R, int C) {
  __shared__ float tile[32][33];
  int c0 = blockIdx.x * 32, r0 = blockIdx.y * 32;
  int tx = threadIdx.x & 31, ty = threadIdx.x >> 5;
#pragma unroll
  for (int k = 0; k < 4; ++k)
    tile[ty + 8 * k][tx] = in[(size_t)(r0 + ty + 8 * k) * C + c0 + tx];
  __syncthreads();
#pragma unroll
  for (int k = 0; k < 4; ++k)
    out[(size_t)(c0 + ty + 8 * k) * R + r0 + tx] = tile[tx][ty + 8 * k];
}

// three 192x1024 transposes in one launch
__global__ __launch_bounds__(256) void k_tr3(const float* __restrict__ A0, const float* __restrict__ A1,
                                             const float* __restrict__ A2,
                                             float* __restrict__ O0, float* __restrict__ O1,
                                             float* __restrict__ O2) {
  const float* in = blockIdx.z == 0 ? A0 : (blockIdx.z == 1 ? A1 : A2);
  float* out = blockIdx.z == 0 ? O0 : (blockIdx.z == 1 ? O1 : O2);
  const int R = 192, C = 1024;
  __shared__ float tile[32][33];
  int c0 = blockIdx.x * 32, r0 = blockIdx.y * 32;
  int tx = threadIdx.x & 31, ty = threadIdx.x >> 5;
#pragma unroll
  for (int k = 0; k < 4; ++k)
    tile[ty + 8 * k][tx] = in[(size_t)(r0 + ty + 8 * k) * C + c0 + tx];
  __syncthreads();
#pragma unroll
  for (int k = 0; k < 4; ++k)
    out[(size_t)(c0 + ty + 8 * k) * R + r0 + tx] = tile[tx][ty + 8 * k];
}

// ---------------- generic small GEMM: C = alpha*(A @ Bt^T) [+ Dm], bf16 MFMA ----------------
template <bool OBF>
__global__ __launch_bounds__(256) void k_gemm_small(
    const float* __restrict__ A, int lda, long sA1, long sA2,
    const float* __restrict__ Bt, int ldb, long sB1, long sB2,
    void* __restrict__ Cv, int ldc, long sC1, long sC2,
    const float* __restrict__ Dm, int ldd,
    int M, int Mv, int N, int K, float alpha, int Z2) {
  int z = blockIdx.z, z1 = z / Z2, z2 = z - z1 * Z2;
  A  += z1 * sA1 + z2 * sA2;
  Bt += z1 * sB1 + z2 * sB2;
  long cbase = z1 * sC1 + z2 * sC2;
  __shared__ short As[64 * 40];
  __shared__ short Bs[64 * 40];
  int t = threadIdx.x, lane = t & 63, wid = t >> 6;
  int wm = wid >> 1, wn = wid & 1;
  int m0 = blockIdx.x * 64, n0 = blockIdx.y * 64;
  f4 acc[2][2] = {};
  int srow = t >> 2, skc = (t & 3) * 8;
  for (int k0 = 0; k0 < K; k0 += 32) {
    __syncthreads();
    f4 a0 = {0,0,0,0}, a1 = {0,0,0,0}, b0 = {0,0,0,0}, b1 = {0,0,0,0};
    if (m0 + srow < Mv) {
      const float* p = A + (size_t)(m0 + srow) * lda + k0 + skc;
      a0 = *(const f4*)p; a1 = *(const f4*)(p + 4);
    }
    if (n0 + srow < N) {
      const float* p = Bt + (size_t)(n0 + srow) * ldb + k0 + skc;
      b0 = *(const f4*)p; b1 = *(const f4*)(p + 4);
    }
    us8 ua, ub;
#pragma unroll
    for (int j = 0; j < 4; ++j) {
      ua[j] = f2bf(a0[j]); ua[4 + j] = f2bf(a1[j]);
      ub[j] = f2bf(b0[j]); ub[4 + j] = f2bf(b1[j]);
    }
    *(us8*)(As + srow * 40 + skc) = ua;
    *(us8*)(Bs + srow * 40 + skc) = ub;
    __syncthreads();
    short8 fa[2], fb[2];
#pragma unroll
    for (int i = 0; i < 2; ++i) {
      fa[i] = *(const short8*)(As + (wm * 32 + i * 16 + (lane & 15)) * 40 + (lane >> 4) * 8);
      fb[i] = *(const short8*)(Bs + (wn * 32 + i * 16 + (lane & 15)) * 40 + (lane >> 4) * 8);
    }
#pragma unroll
    for (int mi = 0; mi < 2; ++mi)
#pragma unroll
      for (int ni = 0; ni < 2; ++ni)
        acc[mi][ni] = __builtin_amdgcn_mfma_f32_16x16x32_bf16(fa[mi], fb[ni], acc[mi][ni], 0, 0, 0);
  }
#pragma unroll
  for (int mi = 0; mi < 2; ++mi)
#pragma unroll
    for (int ni = 0; ni < 2; ++ni)
#pragma unroll
      for (int j = 0; j < 4; ++j) {
        int row = m0 + wm * 32 + mi * 16 + (lane >> 4) * 4 + j;
        int col = n0 + wn * 32 + ni * 16 + (lane & 15);
        if (row < M && col < N) {
          float val = acc[mi][ni][j] * alpha;
          if (Dm) val += Dm[(size_t)row * ldd + col];
          size_t idx = (size_t)cbase + (size_t)row * ldc + col;
          if (OBF) ((unsigned short*)Cv)[idx] = f2bf(val);
          else     ((float*)Cv)[idx] = val;
        }
      }
}

// ---------------- mu/alpha/beta per (b,h,s), with qmean GEMM fused ----------------
__global__ void k_mubeta(const float* __restrict__ hssum, const float* __restrict__ Wq,
                         const float* __restrict__ kv,
                         const int* __restrict__ sb, const int* __restrict__ sn,
                         const float* __restrict__ csf_p,
                         float* __restrict__ alphav, float* __restrict__ betav) {
  int h = blockIdx.x, b = blockIdx.y;
  int t = threadIdx.x;                       // 128 threads
  __shared__ float qp[64];
  // qp[hd] = (1/4096) sum_d hssum[b,d] * Wq[h*64+hd, d]
  {
    int hd = t >> 1, half = t & 1;
    const float* wr = Wq + (size_t)(h * 64 + hd) * D_ + half * 512;
    const float* hp = hssum + b * D_ + half * 512;
    float s = 0.f;
    for (int d = 0; d < 512; d += 4) {
      f4 w = *(const f4*)(wr + d);
      f4 x = *(const f4*)(hp + d);
      s += w[0] * x[0] + w[1] * x[1] + w[2] * x[2] + w[3] * x[3];
    }
    s += __shfl_xor(s, 1, 64);
    if (half == 0) qp[hd] = s * (1.f / 4096.f);
  }
  __syncthreads();
  int s = t;
  if (s >= SP_) return;
  const float* kp = kv + ((size_t)(b * SP_ + s)) * 2048 + h * HD_;
  float mu = 0.f;
#pragma unroll 8
  for (int hd = 0; hd < HD_; ++hd) mu += qp[hd] * kp[hd];
  mu *= 0.125f;
  bool subj = false;
  for (int i = 0; i < NSUBJ_; ++i) subj = subj || (sb[i] == b && sn[i] == s);
  float csf = *csf_p;
  int c = b * NC_ + h * SP_ + s;
  alphav[c] = subj ? csf : 1.f;
  betav[c] = (s >= S_) ? -1e30f : (subj ? -mu * csf : 0.f);
}

// ---------------- C: score GEMM + per-head softmax -> P bf16 ----------------
// T2 XOR chunk swizzle + T3 minimal 2-phase counted-vmcnt double-buffer.
#define CBM 128
#define CBN 160
template <bool AHSB>
__global__ __launch_bounds__(256) void k_score(
    const void* __restrict__ Aany, const unsigned short* __restrict__ Mt,
    const float* __restrict__ alphav, const float* __restrict__ betav,
    unsigned short* __restrict__ P) {
  int id = blockIdx.x;
  int x = id & 7, idp = id >> 3;
  int n_t = idp & 7;
  int pid = (idp >> 3) * 8 + x;     // [0,256): XCD sweeps n_t for a fixed (b,m)-panel
  int b = pid >> 5, m_t = pid & 31;
  int m0 = m_t * CBM, n0 = n_t * CBN;

  const unsigned short* Abf = (const unsigned short*)Aany + (size_t)b * LQ_ * D_;
  const float*          Af  = (const float*)Aany + (size_t)b * LQ_ * D_;
  const unsigned short* Bb  = Mt + (size_t)b * NC_ * D_;
  const float* alp = alphav + b * NC_;
  const float* bet = betav + b * NC_;
  unsigned short* Pb = P + (size_t)b * LQ_ * NC_;

  __shared__ short As[2][CBM * 64];
  __shared__ short Bs[2][CBN * 64];

  int t = threadIdx.x, lane = t & 63, wid = t >> 6;
  int wm = wid >> 1, wn = wid & 1;
  int srow = lane >> 3;                         // 0..7 within an 8-row group
  int schunk = (lane & 7) ^ srow;               // pre-swizzled source chunk
  f4 acc[4][5] = {};
  const int T = D_ / 64;                        // 16

  if constexpr (AHSB) {
    // ---- pipelined path: both operands via global_load_lds, dbuf ----
    // stage tile kt into buffer bf: 5 B-loads + 4 A-loads per thread = 9
    auto STAGE = [&](int bf, int k0) {
      for (int i = wid; i < 20; i += 4)
        gload16(Bb + (size_t)(n0 + i * 8 + srow) * D_ + k0 + schunk * 8,
                (char*)Bs[bf] + i * 1024);
      for (int i = wid; i < 16; i += 4)
        gload16(Abf + (size_t)(m0 + i * 8 + srow) * D_ + k0 + schunk * 8,
                (char*)As[bf] + i * 1024);
    };
    STAGE(0, 0);
    int c = 0;
    for (int kt = 0; kt < T; ++kt) {
      if (kt + 1 < T) {
        STAGE(c ^ 1, (kt + 1) * 64);
        asm volatile("s_waitcnt vmcnt(9)" ::: "memory");   // tile kt complete
      } else {
        asm volatile("s_waitcnt vmcnt(0)" ::: "memory");
      }
      __builtin_amdgcn_s_barrier();
#pragma unroll
      for (int kk = 0; kk < 2; ++kk) {
        int co = ((kk * 4 + (lane >> 4)) ^ (lane & 7)) * 8;
        short8 fa[4], fb[5];
#pragma unroll
        for (int mi = 0; mi < 4; ++mi)
          fa[mi] = *(const short8*)(&As[c][0] + (wm * 64 + mi * 16 + (lane & 15)) * 64 + co);
#pragma unroll
        for (int ni = 0; ni < 5; ++ni)
          fb[ni] = *(const short8*)(&Bs[c][0] + (wn * 80 + ni * 16 + (lane & 15)) * 64 + co);
#pragma unroll
        for (int mi = 0; mi < 4; ++mi)
#pragma unroll
          for (int ni = 0; ni < 5; ++ni)
            acc[mi][ni] = __builtin_amdgcn_mfma_f32_16x16x32_bf16(fa[mi], fb[ni], acc[mi][ni], 0, 0, 0);
      }
      __builtin_amdgcn_s_barrier();
      c ^= 1;
    }
  } else {
    // ---- fallback (ws too small for hsb): fp32 A reg-staged, single buffer ----
    for (int k0 = 0; k0 < D_; k0 += 64) {
      __syncthreads();
      for (int i = wid; i < 20; i += 4)
        gload16(Bb + (size_t)(n0 + i * 8 + srow) * D_ + k0 + schunk * 8,
                (char*)Bs[0] + i * 1024);
      int arow = t >> 3, ac = t & 7;
      int awc = ac ^ (arow & 7);
#pragma unroll
      for (int p = 0; p < 4; ++p) {
        int row = p * 32 + arow;
        const float* src = Af + (size_t)(m0 + row) * D_ + k0 + ac * 8;
        f4 v0 = *(const f4*)src;
        f4 v1 = *(const f4*)(src + 4);
        us8 u;
#pragma unroll
        for (int j = 0; j < 4; ++j) { u[j] = f2bf(v0[j]); u[4 + j] = f2bf(v1[j]); }
        *(us8*)(&As[0][0] + row * 64 + awc * 8) = u;
      }
      __syncthreads();
#pragma unroll
      for (int kk = 0; kk < 2; ++kk) {
        int co = ((kk * 4 + (lane >> 4)) ^ (lane & 7)) * 8;
        short8 fa[4], fb[5];
#pragma unroll
        for (int mi = 0; mi < 4; ++mi)
          fa[mi] = *(const short8*)(&As[0][0] + (wm * 64 + mi * 16 + (lane & 15)) * 64 + co);
#pragma unroll
        for (int ni = 0; ni < 5; ++ni)
          fb[ni] = *(const short8*)(&Bs[0][0] + (wn * 80 + ni * 16 + (lane & 15)) * 64 + co);
#pragma unroll
        for (int mi = 0; mi < 4; ++mi)
#pragma unroll
          for (int ni = 0; ni < 5; ++ni)
            acc[mi][ni] = __builtin_amdgcn_mfma_f32_16x16x32_bf16(fa[mi], fb[ni], acc[mi][ni], 0, 0, 0);
      }
    }
  }

  // epilogue: score' = alpha*score + beta; per-head (80-col) softmax in one wave
  float al[5], be[5];
#pragma unroll
  for (int ni = 0; ni < 5; ++ni) {
    int cc = n0 + wn * 80 + ni * 16 + (lane & 15);
    al[ni] = alp[cc]; be[ni] = bet[cc];
  }
#pragma unroll
  for (int mi = 0; mi < 4; ++mi) {
#pragma unroll
    for (int j = 0; j < 4; ++j) {
      float v[5];
      float m = -3.0e38f;
#pragma unroll
      for (int ni = 0; ni < 5; ++ni) { v[ni] = acc[mi][ni][j] * al[ni] + be[ni]; m = fmaxf(m, v[ni]); }
#pragma unroll
      for (int off = 1; off < 16; off <<= 1) m = fmaxf(m, __shfl_xor(m, off, 64));
      float ssum = 0.f;
#pragma unroll
      for (int ni = 0; ni < 5; ++ni) { v[ni] = __expf(v[ni] - m); ssum += v[ni]; }
#pragma unroll
      for (int off = 1; off < 16; off <<= 1) ssum += __shfl_xor(ssum, off, 64);
      float inv = 1.f / ssum;
      int row = m0 + wm * 64 + mi * 16 + (lane >> 4) * 4 + j;
      size_t rb = (size_t)row * NC_ + n0 + wn * 80 + (lane & 15);
#pragma unroll
      for (int ni = 0; ni < 5; ++ni)
        Pb[rb + ni * 16] = f2bf(v[ni] * inv);
    }
  }
}

// ---------------- D: out = P @ Ut^T + bo  (2-phase counted-vmcnt dbuf) ----------------
#define DBM 128
#define DBN 128
__global__ __launch_bounds__(256) void k_out(
    const unsigned short* __restrict__ P, const unsigned short* __restrict__ Ut,
    const float* __restrict__ bo, float* __restrict__ out) {
  int id = blockIdx.x;
  int x = id & 7, idp = id >> 3;
  int n_t = idp & 7;
  int pid = (idp >> 3) * 8 + x;
  int b = pid >> 5, m_t = pid & 31;
  int m0 = m_t * DBM, n0 = n_t * DBN;

  const unsigned short* Ab = P + (size_t)b * LQ_ * NC_;
  const unsigned short* Bb = Ut + (size_t)b * D_ * NC_;
  float* ob = out + (size_t)b * LQ_ * D_;

  __shared__ short As[2][DBM * 64];
  __shared__ short Bs[2][DBN * 64];
  int t = threadIdx.x, lane = t & 63, wid = t >> 6;
  int wm = wid >> 1, wn = wid & 1;
  int srow = lane >> 3;
  int schunk = (lane & 7) ^ srow;
  f4 acc[4][4] = {};
  const int T = NC_ / 64;   // 20

  auto STAGE = [&](int bf, int k0) {    // 8 loads per thread
    for (int i = wid; i < 32; i += 4) {
      if (i < 16)
        gload16(Ab + (size_t)(m0 + i * 8 + srow) * NC_ + k0 + schunk * 8,
                (char*)As[bf] + i * 1024);
      else
        gload16(Bb + (size_t)(n0 + (i - 16) * 8 + srow) * NC_ + k0 + schunk * 8,
                (char*)Bs[bf] + (i - 16) * 1024);
    }
  };
  STAGE(0, 0);
  int c = 0;
  for (int kt = 0; kt < T; ++kt) {
    if (kt + 1 < T) {
      STAGE(c ^ 1, (kt + 1) * 64);
      asm volatile("s_waitcnt vmcnt(8)" ::: "memory");   // tile kt complete
    } else {
      asm volatile("s_waitcnt vmcnt(0)" ::: "memory");
    }
    __builtin_amdgcn_s_barrier();
#pragma unroll
    for (int kk = 0; kk < 2; ++kk) {
      int co = ((kk * 4 + (lane >> 4)) ^ (lane & 7)) * 8;
      short8 fa[4], fb[4];
#pragma unroll
      for (int mi = 0; mi < 4; ++mi)
        fa[mi] = *(const short8*)(&As[c][0] + (wm * 64 + mi * 16 + (lane & 15)) * 64 + co);
#pragma unroll
      for (int ni = 0; ni < 4; ++ni)
        fb[ni] = *(const short8*)(&Bs[c][0] + (wn * 64 + ni * 16 + (lane & 15)) * 64 + co);
#pragma unroll
      for (int mi = 0; mi < 4; ++mi)
#pragma unroll
        for (int ni = 0; ni < 4; ++ni)
          acc[mi][ni] = __builtin_amdgcn_mfma_f32_16x16x32_bf16(fa[mi], fb[ni], acc[mi][ni], 0, 0, 0);
    }
    __builtin_amdgcn_s_barrier();
    c ^= 1;
  }
#pragma unroll
  for (int ni = 0; ni < 4; ++ni) {
    int col = n0 + wn * 64 + ni * 16 + (lane & 15);
    float bov = bo[col];
#pragma unroll
    for (int mi = 0; mi < 4; ++mi)
#pragma unroll
      for (int j = 0; j < 4; ++j) {
        int row = m0 + wm * 64 + mi * 16 + (lane >> 4) * 4 + j;
        ob[(size_t)row * D_ + col] = acc[mi][ni][j] + bov;
      }
  }
}

extern "C" void kernel_launch(void* const* d_in, const int* in_sizes, int n_in,
                              void* d_out, int out_size, void* d_ws, size_t ws_size,
                              hipStream_t stream) {
  const float* hs  = (const float*)d_in[0];
  const float* ehs = (const float*)d_in[1];
  const float* Wq  = (const float*)d_in[2];
  const float* Wk  = (const float*)d_in[3];
  const float* Wv  = (const float*)d_in[4];
  const float* Wo  = (const float*)d_in[5];
  const float* bo  = (const float*)d_in[6];
  const float* Ak  = (const float*)d_in[7];
  const float* Bk  = (const float*)d_in[8];
  const float* Av  = (const float*)d_in[9];
  const float* Bv  = (const float*)d_in[10];
  const float* Ao  = (const float*)d_in[11];
  const float* Bo  = (const float*)d_in[12];
  const float* csf = (const float*)d_in[13];
  const int*   sb  = (const int*)d_in[14];
  const int*   sn  = (const int*)d_in[15];
  float* out = (float*)d_out;

  char* ws = (char*)d_ws;
  // persistent across the big GEMMs:
  unsigned short* P  = (unsigned short*)ws;                   // 83,886,080
  unsigned short* Mt = (unsigned short*)(ws + 83886080);      // 20,971,520
  unsigned short* Ut = (unsigned short*)(ws + 104857600);     // 20,971,520
  const size_t NEED_HSB = 125829120ULL + 67108864ULL + 81920ULL; // 193,019,904
  bool useHsb = ws_size >= NEED_HSB;
  unsigned short* hsb = useHsb ? (unsigned short*)(ws + 125829120) : nullptr;
  char* tail = useHsb ? (ws + 192937984) : (ws + 125829120);
  float* alphav = (float*)tail;
  float* betav  = (float*)(tail + 40960);
  // temporaries overlapped into P's region (all dead before k_score writes P):
  float* kvbuf = (float*)(ws + 0);            //  5,242,880  [b][80][2048] (k|v)
  float* weff  = (float*)(ws + 5242880);      // 12,582,912  [wkE;wvE;woE]
  float* wqT   = (float*)(ws + 17825792);     //  4,194,304
  float* aT    = (float*)(ws + 22020096);     //  2,359,296
  float* part  = (float*)(ws + 24379392);     //  2,097,152
  float* hssum = (float*)(ws + 26476544);     //     32,768

  float* wkE = weff;                 // rows 0..1023 of a 2048-row [.,1024] view
  float* wvE = weff + 1048576;       // rows 1024..2047
  float* woE = weff + 2097152;
  float* akT = aT;
  float* avT = aT + 196608;
  float* aoT = aT + 393216;

  const float LS = 16.0f / 192.0f;

  // hs row-sums (deterministic two-stage) + bf16 conversion of hs
  k_hssum<<<dim3(64, 8), 256, 0, stream>>>(hs, part, hsb);
  k_hsred<<<32, 256, 0, stream>>>(part, hssum);

  // transposes: Wq^T and the three LoRA-A^T in one launch
  k_tr<<<dim3(32, 32), 256, 0, stream>>>(Wq, wqT, 1024, 1024);
  k_tr3<<<dim3(32, 6, 3), 256, 0, stream>>>(Ak, Av, Ao, akT, avT, aoT);

  // W_eff = W + (1/12) Bx@Ax
  k_gemm_small<false><<<dim3(16, 16, 1), 256, 0, stream>>>(
      Bk, 192, 0, 0, akT, 192, 0, 0, wkE, 1024, 0, 0, Wk, 1024,
      1024, 1024, 1024, 192, LS, 1);
  k_gemm_small<false><<<dim3(16, 16, 1), 256, 0, stream>>>(
      Bv, 192, 0, 0, avT, 192, 0, 0, wvE, 1024, 0, 0, Wv, 1024,
      1024, 1024, 1024, 192, LS, 1);
  k_gemm_small<false><<<dim3(16, 16, 1), 256, 0, stream>>>(
      Bo, 192, 0, 0, aoT, 192, 0, 0, woE, 1024, 0, 0, Wo, 1024,
      1024, 1024, 1024, 192, LS, 1);

  // [k|v] = ehs @ [wkE;wvE]^T in ONE GEMM: N=2048, C row-stride 2048
  k_gemm_small<false><<<dim3(2, 32, 8), 256, 0, stream>>>(
      ehs, 1024, 77L * 1024, 0, weff, 1024, 0, 0, kvbuf, 2048, 80L * 2048, 0, nullptr, 0,
      80, 77, 2048, 1024, 1.f, 1);

  // Mt[b,h] = 0.125 * k_bh @ Wq_h   (bf16, [b][h*80+s][d])
  k_gemm_small<true><<<dim3(2, 16, 128), 256, 0, stream>>>(
      kvbuf, 2048, 80L * 2048, 64L, wqT, 1024, 0, 64L,
      Mt, 1024, (long)NC_ * 1024, 80L * 1024, nullptr, 0,
      80, 80, 1024, 64, 0.125f, 16);

  // Ut[b,h] = Wo_eff_h @ v_bh^T   (bf16, [b][e][h*80+s])
  k_gemm_small<true><<<dim3(16, 2, 128), 256, 0, stream>>>(
      woE, 1024, 0, 64L, kvbuf + 1024, 2048, 80L * 2048, 64L,
      Ut, NC_, 1024L * NC_, 80L, nullptr, 0,
      1024, 1024, 80, 64, 1.f, 16);

  // per-(b,h,s) column mean (qmean fused) + subject alpha/beta
  k_mubeta<<<dim3(16, 8), 128, 0, stream>>>(hssum, Wq, kvbuf, sb, sn, csf, alphav, betav);

  // big fused GEMMs
  if (useHsb)
    k_score<true><<<2048, 256, 0, stream>>>(hsb, Mt, alphav, betav, P);
  else
    k_score<false><<<2048, 256, 0, stream>>>(hs, Mt, alphav, betav, P);
  k_out<<<2048, 256, 0, stream>>>(P, Ut, bo, out);

  (void)in_sizes; (void)n_in; (void)out_size; (void)ws_size;
}

// Round 4
// 374.214 us; speedup vs baseline: 1.4166x; 1.1461x over previous
//
#include <hip/hip_runtime.h>
#include <stdint.h>

#define B_     8
#define LQ_    4096
#define S_     77
#define SP_    80
#define D_     1024
#define H_     16
#define HD_    64
#define NC_    1280   // H_*SP_
#define NSUBJ_ 32

typedef __attribute__((ext_vector_type(4))) float  f4;
typedef __attribute__((ext_vector_type(8))) short  short8;
typedef __attribute__((ext_vector_type(8))) unsigned short us8;
typedef __attribute__((ext_vector_type(4))) unsigned short us4;

__device__ __forceinline__ unsigned short f2bf(float f) {
  union { float f; unsigned u; } x; x.f = f;
  unsigned r = x.u + 0x7FFFu + ((x.u >> 16) & 1u);
  return (unsigned short)(r >> 16);
}

__device__ __forceinline__ void gload16(const void* g, void* s) {
  __builtin_amdgcn_global_load_lds((const __attribute__((address_space(1))) void*)g,
                                   (__attribute__((address_space(3))) void*)s, 16, 0, 0);
}

// ---------------- hssum partials + hs -> bf16 convert ----------------
__global__ __launch_bounds__(256) void k_hssum(const float* __restrict__ hs,
                                               float* __restrict__ part,
                                               unsigned short* __restrict__ hsb) {
  int b = blockIdx.y;
  size_t base = ((size_t)b * LQ_ + (size_t)blockIdx.x * 64) * D_ + threadIdx.x * 4;
  f4 acc = {0.f, 0.f, 0.f, 0.f};
  for (int l = 0; l < 64; ++l) {
    f4 v = *(const f4*)(hs + base + (size_t)l * D_);
    acc += v;
    if (hsb) {
      us4 o;
#pragma unroll
      for (int j = 0; j < 4; ++j) o[j] = f2bf(v[j]);
      *(us4*)(hsb + base + (size_t)l * D_) = o;
    }
  }
  *(f4*)(part + (size_t)blockIdx.x * (B_ * D_) + b * D_ + threadIdx.x * 4) = acc;
}

__global__ __launch_bounds__(256) void k_hsred(const float* __restrict__ part,
                                               float* __restrict__ hssum) {
  int i = blockIdx.x * 256 + threadIdx.x;   // [0, 8192)
  float s = 0.f;
  for (int x = 0; x < 64; ++x) s += part[(size_t)x * (B_ * D_) + i];
  hssum[i] = s;
}

// ---------------- 4 transposes (Wq 1024x1024, Ak/Av/Ao 192x1024) in one launch ----------------
__global__ __launch_bounds__(256) void k_tr4(const float* __restrict__ Wq, const float* __restrict__ Ak,
                                             const float* __restrict__ Av, const float* __restrict__ Ao,
                                             float* __restrict__ wqT, float* __restrict__ akT,
                                             float* __restrict__ avT, float* __restrict__ aoT) {
  int z = blockIdx.z;
  const float* in = z == 0 ? Wq : (z == 1 ? Ak : (z == 2 ? Av : Ao));
  float* out = z == 0 ? wqT : (z == 1 ? akT : (z == 2 ? avT : aoT));
  int R = z == 0 ? 1024 : 192;
  const int C = 1024;
  int c0 = blockIdx.x * 32, r0 = blockIdx.y * 32;
  if (r0 >= R) return;
  __shared__ float tile[32][33];
  int tx = threadIdx.x & 31, ty = threadIdx.x >> 5;
#pragma unroll
  for (int k = 0; k < 4; ++k)
    tile[ty + 8 * k][tx] = in[(size_t)(r0 + ty + 8 * k) * C + c0 + tx];
  __syncthreads();
#pragma unroll
  for (int k = 0; k < 4; ++k)
    out[(size_t)(c0 + ty + 8 * k) * R + r0 + tx] = tile[tx][ty + 8 * k];
}

// ---------------- shared 64x64-tile GEMM body: C = alpha*(A @ Bt^T) [+ Dm] ----------------
template <bool OBF>
__device__ __forceinline__ void gemm64_body(
    const float* __restrict__ A, int lda, const float* __restrict__ Bt, int ldb,
    void* __restrict__ Cv, int ldc, long cbase, const float* __restrict__ Dm, int ldd,
    int M, int Mv, int N, int K, float alpha, int m0, int n0,
    short* As, short* Bs) {
  int t = threadIdx.x, lane = t & 63, wid = t >> 6;
  int wm = wid >> 1, wn = wid & 1;
  f4 acc[2][2] = {};
  int srow = t >> 2, skc = (t & 3) * 8;
  for (int k0 = 0; k0 < K; k0 += 32) {
    __syncthreads();
    f4 a0 = {0,0,0,0}, a1 = {0,0,0,0}, b0 = {0,0,0,0}, b1 = {0,0,0,0};
    if (m0 + srow < Mv) {
      const float* p = A + (size_t)(m0 + srow) * lda + k0 + skc;
      a0 = *(const f4*)p; a1 = *(const f4*)(p + 4);
    }
    if (n0 + srow < N) {
      const float* p = Bt + (size_t)(n0 + srow) * ldb + k0 + skc;
      b0 = *(const f4*)p; b1 = *(const f4*)(p + 4);
    }
    us8 ua, ub;
#pragma unroll
    for (int j = 0; j < 4; ++j) {
      ua[j] = f2bf(a0[j]); ua[4 + j] = f2bf(a1[j]);
      ub[j] = f2bf(b0[j]); ub[4 + j] = f2bf(b1[j]);
    }
    *(us8*)(As + srow * 40 + skc) = ua;
    *(us8*)(Bs + srow * 40 + skc) = ub;
    __syncthreads();
    short8 fa[2], fb[2];
#pragma unroll
    for (int i = 0; i < 2; ++i) {
      fa[i] = *(const short8*)(As + (wm * 32 + i * 16 + (lane & 15)) * 40 + (lane >> 4) * 8);
      fb[i] = *(const short8*)(Bs + (wn * 32 + i * 16 + (lane & 15)) * 40 + (lane >> 4) * 8);
    }
#pragma unroll
    for (int mi = 0; mi < 2; ++mi)
#pragma unroll
      for (int ni = 0; ni < 2; ++ni)
        acc[mi][ni] = __builtin_amdgcn_mfma_f32_16x16x32_bf16(fa[mi], fb[ni], acc[mi][ni], 0, 0, 0);
  }
#pragma unroll
  for (int mi = 0; mi < 2; ++mi)
#pragma unroll
    for (int ni = 0; ni < 2; ++ni)
#pragma unroll
      for (int j = 0; j < 4; ++j) {
        int row = m0 + wm * 32 + mi * 16 + (lane >> 4) * 4 + j;
        int col = n0 + wn * 32 + ni * 16 + (lane & 15);
        if (row < M && col < N) {
          float val = acc[mi][ni][j] * alpha;
          if (Dm) val += Dm[(size_t)row * ldd + col];
          size_t idx = (size_t)cbase + (size_t)row * ldc + col;
          if (OBF) ((unsigned short*)Cv)[idx] = f2bf(val);
          else     ((float*)Cv)[idx] = val;
        }
      }
}

template <bool OBF>
__global__ __launch_bounds__(256) void k_gemm_small(
    const float* __restrict__ A, int lda, long sA1, long sA2,
    const float* __restrict__ Bt, int ldb, long sB1, long sB2,
    void* __restrict__ Cv, int ldc, long sC1, long sC2,
    const float* __restrict__ Dm, int ldd,
    int M, int Mv, int N, int K, float alpha, int Z2) {
  int z = blockIdx.z, z1 = z / Z2, z2 = z - z1 * Z2;
  __shared__ short As[64 * 40];
  __shared__ short Bs[64 * 40];
  gemm64_body<OBF>(A + z1 * sA1 + z2 * sA2, lda, Bt + z1 * sB1 + z2 * sB2, ldb,
                   Cv, ldc, z1 * sC1 + z2 * sC2, Dm, ldd, M, Mv, N, K, alpha,
                   blockIdx.x * 64, blockIdx.y * 64, As, Bs);
}

// W_eff = W + (1/12) Bx@Ax : three GEMMs in one launch (z selects k/v/o)
__global__ __launch_bounds__(256) void k_weff(
    const float* __restrict__ Bk, const float* __restrict__ Bv, const float* __restrict__ Bo,
    const float* __restrict__ akT, const float* __restrict__ avT, const float* __restrict__ aoT,
    const float* __restrict__ Wk, const float* __restrict__ Wv, const float* __restrict__ Wo,
    float* __restrict__ weff, float alpha) {
  int z = blockIdx.z;
  const float* A  = z == 0 ? Bk : (z == 1 ? Bv : Bo);
  const float* Bt = z == 0 ? akT : (z == 1 ? avT : aoT);
  const float* Dm = z == 0 ? Wk : (z == 1 ? Wv : Wo);
  __shared__ short As[64 * 40];
  __shared__ short Bs[64 * 40];
  gemm64_body<false>(A, 192, Bt, 192, weff + (size_t)z * 1048576, 1024, 0, Dm, 1024,
                     1024, 1024, 1024, 192, alpha, blockIdx.x * 64, blockIdx.y * 64, As, Bs);
}

// ---------------- mu/alpha/beta per (b,h,s), with qmean GEMM fused ----------------
__global__ void k_mubeta(const float* __restrict__ hssum, const float* __restrict__ Wq,
                         const float* __restrict__ kv,
                         const int* __restrict__ sb, const int* __restrict__ sn,
                         const float* __restrict__ csf_p,
                         float* __restrict__ alphav, float* __restrict__ betav) {
  int h = blockIdx.x, b = blockIdx.y;
  int t = threadIdx.x;                       // 128 threads
  __shared__ float qp[64];
  {
    int hd = t >> 1, half = t & 1;
    const float* wr = Wq + (size_t)(h * 64 + hd) * D_ + half * 512;
    const float* hp = hssum + b * D_ + half * 512;
    float s = 0.f;
    for (int d = 0; d < 512; d += 4) {
      f4 w = *(const f4*)(wr + d);
      f4 x = *(const f4*)(hp + d);
      s += w[0] * x[0] + w[1] * x[1] + w[2] * x[2] + w[3] * x[3];
    }
    s += __shfl_xor(s, 1, 64);
    if (half == 0) qp[hd] = s * (1.f / 4096.f);
  }
  __syncthreads();
  int s = t;
  if (s >= SP_) return;
  const float* kp = kv + ((size_t)(b * SP_ + s)) * 2048 + h * HD_;
  float mu = 0.f;
#pragma unroll 8
  for (int hd = 0; hd < HD_; ++hd) mu += qp[hd] * kp[hd];
  mu *= 0.125f;
  bool subj = false;
  for (int i = 0; i < NSUBJ_; ++i) subj = subj || (sb[i] == b && sn[i] == s);
  float csf = *csf_p;
  int c = b * NC_ + h * SP_ + s;
  alphav[c] = subj ? csf : 1.f;
  betav[c] = (s >= S_) ? -1e30f : (subj ? -mu * csf : 0.f);
}

// ---------------- big score GEMM 256x320, 512 thr, 2-phase counted-vmcnt ----------------
// waves 2M x 4N: wave tile 128x80 (one head per wave). XOR chunk swizzle both sides.
__global__ __launch_bounds__(512, 2) void k_score_big(
    const unsigned short* __restrict__ hsb, const unsigned short* __restrict__ Mt,
    const float* __restrict__ alphav, const float* __restrict__ betav,
    unsigned short* __restrict__ P) {
  extern __shared__ short lds[];
  const int ASZ = 256 * 64;   // shorts
  const int BSZ = 320 * 64;
  int id = blockIdx.x;
  int x = id & 7, idp = id >> 3;
  int nt = idp & 3;
  int pid = (idp >> 2) * 8 + x;    // [0,128)
  int b = pid >> 4, mt = pid & 15;
  int m0 = mt * 256, n0 = nt * 320;

  const unsigned short* Ab = hsb + (size_t)b * LQ_ * D_;
  const unsigned short* Bb = Mt + (size_t)b * NC_ * D_;
  const float* alp = alphav + b * NC_;
  const float* bet = betav + b * NC_;
  unsigned short* Pb = P + (size_t)b * LQ_ * NC_;

  int t = threadIdx.x, lane = t & 63, wid = t >> 6;   // 8 waves
  int wm = wid >> 2, wn = wid & 3;
  f4 acc[8][5] = {};

  auto STAGE = [&](int bf, int k0) {   // 9 loads/thread (uniform across waves)
#pragma unroll
    for (int p = 0; p < 4; ++p) {      // A: 2048 chunks
      int cb = p * 512 + wid * 64;     // wave-uniform
      int c = cb + lane;
      int row = c >> 3, col = ((c & 7) ^ (row & 7)) * 8;
      gload16(Ab + (size_t)(m0 + row) * D_ + k0 + col, (char*)(lds + bf * ASZ) + cb * 16);
    }
#pragma unroll
    for (int p = 0; p < 5; ++p) {      // B: 2560 chunks
      int cb = p * 512 + wid * 64;
      int c = cb + lane;
      int row = c >> 3, col = ((c & 7) ^ (row & 7)) * 8;
      gload16(Bb + (size_t)(n0 + row) * D_ + k0 + col, (char*)(lds + 2 * ASZ + bf * BSZ) + cb * 16);
    }
  };

  STAGE(0, 0);
  int c = 0;
  for (int kt = 0; kt < 16; ++kt) {
    if (kt < 15) {
      STAGE(c ^ 1, (kt + 1) * 64);
      asm volatile("s_waitcnt vmcnt(9)" ::: "memory");   // tile kt complete
    } else {
      asm volatile("s_waitcnt vmcnt(0)" ::: "memory");
    }
    __builtin_amdgcn_s_barrier();
    const short* Ar = lds + c * ASZ;
    const short* Br = lds + 2 * ASZ + c * BSZ;
    __builtin_amdgcn_s_setprio(1);
#pragma unroll
    for (int kk = 0; kk < 2; ++kk) {
      int co = ((kk * 4 + (lane >> 4)) ^ (lane & 7)) * 8;
      short8 fb[5];
#pragma unroll
      for (int ni = 0; ni < 5; ++ni)
        fb[ni] = *(const short8*)(Br + (wn * 80 + ni * 16 + (lane & 15)) * 64 + co);
#pragma unroll
      for (int mi = 0; mi < 8; ++mi) {
        short8 fa = *(const short8*)(Ar + (wm * 128 + mi * 16 + (lane & 15)) * 64 + co);
#pragma unroll
        for (int ni = 0; ni < 5; ++ni)
          acc[mi][ni] = __builtin_amdgcn_mfma_f32_16x16x32_bf16(fa, fb[ni], acc[mi][ni], 0, 0, 0);
      }
    }
    __builtin_amdgcn_s_setprio(0);
    __builtin_amdgcn_s_barrier();
    c ^= 1;
  }

  // epilogue: alpha*score + beta, per-head softmax (wave owns one 80-col head)
  float al[5], be[5];
#pragma unroll
  for (int ni = 0; ni < 5; ++ni) {
    int cc = n0 + wn * 80 + ni * 16 + (lane & 15);
    al[ni] = alp[cc]; be[ni] = bet[cc];
  }
#pragma unroll
  for (int mi = 0; mi < 8; ++mi) {
#pragma unroll
    for (int j = 0; j < 4; ++j) {
      float v[5];
      float m = -3.0e38f;
#pragma unroll
      for (int ni = 0; ni < 5; ++ni) { v[ni] = acc[mi][ni][j] * al[ni] + be[ni]; m = fmaxf(m, v[ni]); }
#pragma unroll
      for (int off = 1; off < 16; off <<= 1) m = fmaxf(m, __shfl_xor(m, off, 64));
      float ssum = 0.f;
#pragma unroll
      for (int ni = 0; ni < 5; ++ni) { v[ni] = __expf(v[ni] - m); ssum += v[ni]; }
#pragma unroll
      for (int off = 1; off < 16; off <<= 1) ssum += __shfl_xor(ssum, off, 64);
      float inv = 1.f / ssum;
      int row = m0 + wm * 128 + mi * 16 + (lane >> 4) * 4 + j;
      size_t rb = (size_t)row * NC_ + n0 + wn * 80 + (lane & 15);
#pragma unroll
      for (int ni = 0; ni < 5; ++ni)
        Pb[rb + ni * 16] = f2bf(v[ni] * inv);
    }
  }
}

// ---------------- fallback score GEMM (fp32 A, reg-staged), 128x160, 256 thr ----------------
__global__ __launch_bounds__(256) void k_score_f32(
    const float* __restrict__ hs, const unsigned short* __restrict__ Mt,
    const float* __restrict__ alphav, const float* __restrict__ betav,
    unsigned short* __restrict__ P) {
  int id = blockIdx.x;
  int x = id & 7, idp = id >> 3;
  int n_t = idp & 7;
  int pid = (idp >> 3) * 8 + x;
  int b = pid >> 5, m_t = pid & 31;
  int m0 = m_t * 128, n0 = n_t * 160;
  const float* Af = hs + (size_t)b * LQ_ * D_;
  const unsigned short* Bb = Mt + (size_t)b * NC_ * D_;
  const float* alp = alphav + b * NC_;
  const float* bet = betav + b * NC_;
  unsigned short* Pb = P + (size_t)b * LQ_ * NC_;
  __shared__ short As[128 * 64];
  __shared__ short Bs[160 * 64];
  int t = threadIdx.x, lane = t & 63, wid = t >> 6;
  int wm = wid >> 1, wn = wid & 1;
  int srow = lane >> 3;
  int schunk = (lane & 7) ^ srow;
  f4 acc[4][5] = {};
  for (int k0 = 0; k0 < D_; k0 += 64) {
    __syncthreads();
    for (int i = wid; i < 20; i += 4)
      gload16(Bb + (size_t)(n0 + i * 8 + srow) * D_ + k0 + schunk * 8, (char*)Bs + i * 1024);
    int arow = t >> 3, ac = t & 7;
    int awc = ac ^ (arow & 7);
#pragma unroll
    for (int p = 0; p < 4; ++p) {
      int row = p * 32 + arow;
      const float* src = Af + (size_t)(m0 + row) * D_ + k0 + ac * 8;
      f4 v0 = *(const f4*)src;
      f4 v1 = *(const f4*)(src + 4);
      us8 u;
#pragma unroll
      for (int j = 0; j < 4; ++j) { u[j] = f2bf(v0[j]); u[4 + j] = f2bf(v1[j]); }
      *(us8*)(As + row * 64 + awc * 8) = u;
    }
    __syncthreads();
#pragma unroll
    for (int kk = 0; kk < 2; ++kk) {
      int co = ((kk * 4 + (lane >> 4)) ^ (lane & 7)) * 8;
      short8 fa[4], fb[5];
#pragma unroll
      for (int mi = 0; mi < 4; ++mi)
        fa[mi] = *(const short8*)(As + (wm * 64 + mi * 16 + (lane & 15)) * 64 + co);
#pragma unroll
      for (int ni = 0; ni < 5; ++ni)
        fb[ni] = *(const short8*)(Bs + (wn * 80 + ni * 16 + (lane & 15)) * 64 + co);
#pragma unroll
      for (int mi = 0; mi < 4; ++mi)
#pragma unroll
        for (int ni = 0; ni < 5; ++ni)
          acc[mi][ni] = __builtin_amdgcn_mfma_f32_16x16x32_bf16(fa[mi], fb[ni], acc[mi][ni], 0, 0, 0);
    }
  }
  float al[5], be[5];
#pragma unroll
  for (int ni = 0; ni < 5; ++ni) {
    int cc = n0 + wn * 80 + ni * 16 + (lane & 15);
    al[ni] = alp[cc]; be[ni] = bet[cc];
  }
#pragma unroll
  for (int mi = 0; mi < 4; ++mi) {
#pragma unroll
    for (int j = 0; j < 4; ++j) {
      float v[5];
      float m = -3.0e38f;
#pragma unroll
      for (int ni = 0; ni < 5; ++ni) { v[ni] = acc[mi][ni][j] * al[ni] + be[ni]; m = fmaxf(m, v[ni]); }
#pragma unroll
      for (int off = 1; off < 16; off <<= 1) m = fmaxf(m, __shfl_xor(m, off, 64));
      float ssum = 0.f;
#pragma unroll
      for (int ni = 0; ni < 5; ++ni) { v[ni] = __expf(v[ni] - m); ssum += v[ni]; }
#pragma unroll
      for (int off = 1; off < 16; off <<= 1) ssum += __shfl_xor(ssum, off, 64);
      float inv = 1.f / ssum;
      int row = m0 + wm * 64 + mi * 16 + (lane >> 4) * 4 + j;
      size_t rb = (size_t)row * NC_ + n0 + wn * 80 + (lane & 15);
#pragma unroll
      for (int ni = 0; ni < 5; ++ni)
        Pb[rb + ni * 16] = f2bf(v[ni] * inv);
    }
  }
}

// ---------------- big out GEMM 256x256: out = P @ Ut^T + bo ----------------
__global__ __launch_bounds__(512, 2) void k_out_big(
    const unsigned short* __restrict__ P, const unsigned short* __restrict__ Ut,
    const float* __restrict__ bo, float* __restrict__ out) {
  extern __shared__ short lds[];
  const int ASZ = 256 * 64;
  int id = blockIdx.x;
  int x = id & 7, idp = id >> 3;
  int nt = idp & 3;
  int pid = (idp >> 2) * 8 + x;
  int b = pid >> 4, mt = pid & 15;
  int m0 = mt * 256, n0 = nt * 256;

  const unsigned short* Ab = P + (size_t)b * LQ_ * NC_;
  const unsigned short* Bb = Ut + (size_t)b * D_ * NC_;
  float* ob = out + (size_t)b * LQ_ * D_;

  int t = threadIdx.x, lane = t & 63, wid = t >> 6;
  int wm = wid >> 2, wn = wid & 3;
  f4 acc[8][4] = {};
  const int T = NC_ / 64;   // 20

  auto STAGE = [&](int bf, int k0) {   // 8 loads/thread
#pragma unroll
    for (int p = 0; p < 4; ++p) {
      int cb = p * 512 + wid * 64;
      int c = cb + lane;
      int row = c >> 3, col = ((c & 7) ^ (row & 7)) * 8;
      gload16(Ab + (size_t)(m0 + row) * NC_ + k0 + col, (char*)(lds + bf * ASZ) + cb * 16);
    }
#pragma unroll
    for (int p = 0; p < 4; ++p) {
      int cb = p * 512 + wid * 64;
      int c = cb + lane;
      int row = c >> 3, col = ((c & 7) ^ (row & 7)) * 8;
      gload16(Bb + (size_t)(n0 + row) * NC_ + k0 + col, (char*)(lds + 2 * ASZ + bf * ASZ) + cb * 16);
    }
  };

  STAGE(0, 0);
  int c = 0;
  for (int kt = 0; kt < T; ++kt) {
    if (kt + 1 < T) {
      STAGE(c ^ 1, (kt + 1) * 64);
      asm volatile("s_waitcnt vmcnt(8)" ::: "memory");
    } else {
      asm volatile("s_waitcnt vmcnt(0)" ::: "memory");
    }
    __builtin_amdgcn_s_barrier();
    const short* Ar = lds + c * ASZ;
    const short* Br = lds + 2 * ASZ + c * ASZ;
    __builtin_amdgcn_s_setprio(1);
#pragma unroll
    for (int kk = 0; kk < 2; ++kk) {
      int co = ((kk * 4 + (lane >> 4)) ^ (lane & 7)) * 8;
      short8 fb[4];
#pragma unroll
      for (int ni = 0; ni < 4; ++ni)
        fb[ni] = *(const short8*)(Br + (wn * 64 + ni * 16 + (lane & 15)) * 64 + co);
#pragma unroll
      for (int mi = 0; mi < 8; ++mi) {
        short8 fa = *(const short8*)(Ar + (wm * 128 + mi * 16 + (lane & 15)) * 64 + co);
#pragma unroll
        for (int ni = 0; ni < 4; ++ni)
          acc[mi][ni] = __builtin_amdgcn_mfma_f32_16x16x32_bf16(fa, fb[ni], acc[mi][ni], 0, 0, 0);
      }
    }
    __builtin_amdgcn_s_setprio(0);
    __builtin_amdgcn_s_barrier();
    c ^= 1;
  }
#pragma unroll
  for (int ni = 0; ni < 4; ++ni) {
    int col = n0 + wn * 64 + ni * 16 + (lane & 15);
    float bov = bo[col];
#pragma unroll
    for (int mi = 0; mi < 8; ++mi)
#pragma unroll
      for (int j = 0; j < 4; ++j) {
        int row = m0 + wm * 128 + mi * 16 + (lane >> 4) * 4 + j;
        ob[(size_t)row * D_ + col] = acc[mi][ni][j] + bov;
      }
  }
}

extern "C" void kernel_launch(void* const* d_in, const int* in_sizes, int n_in,
                              void* d_out, int out_size, void* d_ws, size_t ws_size,
                              hipStream_t stream) {
  const float* hs  = (const float*)d_in[0];
  const float* ehs = (const float*)d_in[1];
  const float* Wq  = (const float*)d_in[2];
  const float* Wk  = (const float*)d_in[3];
  const float* Wv  = (const float*)d_in[4];
  const float* Wo  = (const float*)d_in[5];
  const float* bo  = (const float*)d_in[6];
  const float* Ak  = (const float*)d_in[7];
  const float* Bk  = (const float*)d_in[8];
  const float* Av  = (const float*)d_in[9];
  const float* Bv  = (const float*)d_in[10];
  const float* Ao  = (const float*)d_in[11];
  const float* Bo  = (const float*)d_in[12];
  const float* csf = (const float*)d_in[13];
  const int*   sb  = (const int*)d_in[14];
  const int*   sn  = (const int*)d_in[15];
  float* out = (float*)d_out;

  hipFuncSetAttribute(reinterpret_cast<const void*>(k_score_big),
                      hipFuncAttributeMaxDynamicSharedMemorySize, 147456);
  hipFuncSetAttribute(reinterpret_cast<const void*>(k_out_big),
                      hipFuncAttributeMaxDynamicSharedMemorySize, 131072);

  char* ws = (char*)d_ws;
  unsigned short* P  = (unsigned short*)ws;                   // 83,886,080
  unsigned short* Mt = (unsigned short*)(ws + 83886080);      // 20,971,520
  unsigned short* Ut = (unsigned short*)(ws + 104857600);     // 20,971,520
  const size_t NEED_HSB = 125829120ULL + 67108864ULL + 81920ULL; // 193,019,904
  bool useHsb = ws_size >= NEED_HSB;
  unsigned short* hsb = useHsb ? (unsigned short*)(ws + 125829120) : nullptr;
  char* tail = useHsb ? (ws + 192937984) : (ws + 125829120);
  float* alphav = (float*)tail;
  float* betav  = (float*)(tail + 40960);
  // temporaries overlapped into P's region (all dead before k_score writes P):
  float* kvbuf = (float*)(ws + 0);            //  5,242,880  [b][80][2048] (k|v)
  float* weff  = (float*)(ws + 5242880);      // 12,582,912  [wkE;wvE;woE]
  float* wqT   = (float*)(ws + 17825792);     //  4,194,304
  float* aT    = (float*)(ws + 22020096);     //  2,359,296
  float* part  = (float*)(ws + 24379392);     //  2,097,152
  float* hssum = (float*)(ws + 26476544);     //     32,768

  float* woE = weff + 2097152;
  float* akT = aT;
  float* avT = aT + 196608;
  float* aoT = aT + 393216;

  const float LS = 16.0f / 192.0f;

  // hs row-sums (deterministic two-stage) + bf16 conversion of hs
  k_hssum<<<dim3(64, 8), 256, 0, stream>>>(hs, part, hsb);
  k_hsred<<<32, 256, 0, stream>>>(part, hssum);

  // all transposes in one launch
  k_tr4<<<dim3(32, 32, 4), 256, 0, stream>>>(Wq, Ak, Av, Ao, wqT, akT, avT, aoT);

  // W_eff (k,v,o) in one launch
  k_weff<<<dim3(16, 16, 3), 256, 0, stream>>>(Bk, Bv, Bo, akT, avT, aoT, Wk, Wv, Wo, weff, LS);

  // [k|v] = ehs @ [wkE;wvE]^T : N=2048, C row-stride 2048
  k_gemm_small<false><<<dim3(2, 32, 8), 256, 0, stream>>>(
      ehs, 1024, 77L * 1024, 0, weff, 1024, 0, 0, kvbuf, 2048, 80L * 2048, 0, nullptr, 0,
      80, 77, 2048, 1024, 1.f, 1);

  // Mt[b,h] = 0.125 * k_bh @ Wq_h   (bf16, [b][h*80+s][d])
  k_gemm_small<true><<<dim3(2, 16, 128), 256, 0, stream>>>(
      kvbuf, 2048, 80L * 2048, 64L, wqT, 1024, 0, 64L,
      Mt, 1024, (long)NC_ * 1024, 80L * 1024, nullptr, 0,
      80, 80, 1024, 64, 0.125f, 16);

  // Ut[b,h] = Wo_eff_h @ v_bh^T   (bf16, [b][e][h*80+s])
  k_gemm_small<true><<<dim3(16, 2, 128), 256, 0, stream>>>(
      woE, 1024, 0, 64L, kvbuf + 1024, 2048, 80L * 2048, 64L,
      Ut, NC_, 1024L * NC_, 80L, nullptr, 0,
      1024, 1024, 80, 64, 1.f, 16);

  // per-(b,h,s) column mean (qmean fused) + subject alpha/beta
  k_mubeta<<<dim3(16, 8), 128, 0, stream>>>(hssum, Wq, kvbuf, sb, sn, csf, alphav, betav);

  // big fused GEMMs
  if (useHsb)
    k_score_big<<<512, 512, 147456, stream>>>(hsb, Mt, alphav, betav, P);
  else
    k_score_f32<<<2048, 256, 0, stream>>>(hs, Mt, alphav, betav, P);
  k_out_big<<<512, 512, 131072, stream>>>(P, Ut, bo, out);

  (void)in_sizes; (void)n_in; (void)out_size; (void)ws_size;
}

// Round 5
// 364.567 us; speedup vs baseline: 1.4541x; 1.0265x over previous
//
#include <hip/hip_runtime.h>
#include <stdint.h>

#define B_     8
#define LQ_    4096
#define S_     77
#define SP_    80
#define D_     1024
#define H_     16
#define HD_    64
#define NC_    1280   // H_*SP_
#define NSUBJ_ 32

typedef __attribute__((ext_vector_type(4))) float  f4;
typedef __attribute__((ext_vector_type(8))) short  short8;
typedef __attribute__((ext_vector_type(8))) unsigned short us8;
typedef __attribute__((ext_vector_type(4))) unsigned short us4;

__device__ __forceinline__ unsigned short f2bf(float f) {
  union { float f; unsigned u; } x; x.f = f;
  unsigned r = x.u + 0x7FFFu + ((x.u >> 16) & 1u);
  return (unsigned short)(r >> 16);
}

__device__ __forceinline__ void gload16(const void* g, void* s) {
  __builtin_amdgcn_global_load_lds((const __attribute__((address_space(1))) void*)g,
                                   (__attribute__((address_space(3))) void*)s, 16, 0, 0);
}

// ---------------- hssum partials + hs -> bf16 convert ----------------
__global__ __launch_bounds__(256) void k_hssum(const float* __restrict__ hs,
                                               float* __restrict__ part,
                                               unsigned short* __restrict__ hsb) {
  int b = blockIdx.y;
  size_t base = ((size_t)b * LQ_ + (size_t)blockIdx.x * 64) * D_ + threadIdx.x * 4;
  f4 acc = {0.f, 0.f, 0.f, 0.f};
  for (int l = 0; l < 64; ++l) {
    f4 v = *(const f4*)(hs + base + (size_t)l * D_);
    acc += v;
    if (hsb) {
      us4 o;
#pragma unroll
      for (int j = 0; j < 4; ++j) o[j] = f2bf(v[j]);
      *(us4*)(hsb + base + (size_t)l * D_) = o;
    }
  }
  *(f4*)(part + (size_t)blockIdx.x * (B_ * D_) + b * D_ + threadIdx.x * 4) = acc;
}

__global__ __launch_bounds__(256) void k_hsred(const float* __restrict__ part,
                                               float* __restrict__ hssum) {
  int i = blockIdx.x * 256 + threadIdx.x;   // [0, 8192)
  float s = 0.f;
  for (int x = 0; x < 64; ++x) s += part[(size_t)x * (B_ * D_) + i];
  hssum[i] = s;
}

// ---------------- 4 transposes (Wq 1024x1024, Ak/Av/Ao 192x1024) in one launch ----------------
__global__ __launch_bounds__(256) void k_tr4(const float* __restrict__ Wq, const float* __restrict__ Ak,
                                             const float* __restrict__ Av, const float* __restrict__ Ao,
                                             float* __restrict__ wqT, float* __restrict__ akT,
                                             float* __restrict__ avT, float* __restrict__ aoT) {
  int z = blockIdx.z;
  const float* in = z == 0 ? Wq : (z == 1 ? Ak : (z == 2 ? Av : Ao));
  float* out = z == 0 ? wqT : (z == 1 ? akT : (z == 2 ? avT : aoT));
  int R = z == 0 ? 1024 : 192;
  const int C = 1024;
  int c0 = blockIdx.x * 32, r0 = blockIdx.y * 32;
  if (r0 >= R) return;
  __shared__ float tile[32][33];
  int tx = threadIdx.x & 31, ty = threadIdx.x >> 5;
#pragma unroll
  for (int k = 0; k < 4; ++k)
    tile[ty + 8 * k][tx] = in[(size_t)(r0 + ty + 8 * k) * C + c0 + tx];
  __syncthreads();
#pragma unroll
  for (int k = 0; k < 4; ++k)
    out[(size_t)(c0 + ty + 8 * k) * R + r0 + tx] = tile[tx][ty + 8 * k];
}

// ---------------- shared 64x64-tile GEMM body: C = alpha*(A @ Bt^T) [+ Dm] ----------------
template <bool OBF>
__device__ __forceinline__ void gemm64_body(
    const float* __restrict__ A, int lda, const float* __restrict__ Bt, int ldb,
    void* __restrict__ Cv, int ldc, long cbase, const float* __restrict__ Dm, int ldd,
    int M, int Mv, int N, int K, float alpha, int m0, int n0,
    short* As, short* Bs) {
  int t = threadIdx.x, lane = t & 63, wid = t >> 6;
  int wm = wid >> 1, wn = wid & 1;
  f4 acc[2][2] = {};
  int srow = t >> 2, skc = (t & 3) * 8;
  for (int k0 = 0; k0 < K; k0 += 32) {
    __syncthreads();
    f4 a0 = {0,0,0,0}, a1 = {0,0,0,0}, b0 = {0,0,0,0}, b1 = {0,0,0,0};
    if (m0 + srow < Mv) {
      const float* p = A + (size_t)(m0 + srow) * lda + k0 + skc;
      a0 = *(const f4*)p; a1 = *(const f4*)(p + 4);
    }
    if (n0 + srow < N) {
      const float* p = Bt + (size_t)(n0 + srow) * ldb + k0 + skc;
      b0 = *(const f4*)p; b1 = *(const f4*)(p + 4);
    }
    us8 ua, ub;
#pragma unroll
    for (int j = 0; j < 4; ++j) {
      ua[j] = f2bf(a0[j]); ua[4 + j] = f2bf(a1[j]);
      ub[j] = f2bf(b0[j]); ub[4 + j] = f2bf(b1[j]);
    }
    *(us8*)(As + srow * 40 + skc) = ua;
    *(us8*)(Bs + srow * 40 + skc) = ub;
    __syncthreads();
    short8 fa[2], fb[2];
#pragma unroll
    for (int i = 0; i < 2; ++i) {
      fa[i] = *(const short8*)(As + (wm * 32 + i * 16 + (lane & 15)) * 40 + (lane >> 4) * 8);
      fb[i] = *(const short8*)(Bs + (wn * 32 + i * 16 + (lane & 15)) * 40 + (lane >> 4) * 8);
    }
#pragma unroll
    for (int mi = 0; mi < 2; ++mi)
#pragma unroll
      for (int ni = 0; ni < 2; ++ni)
        acc[mi][ni] = __builtin_amdgcn_mfma_f32_16x16x32_bf16(fa[mi], fb[ni], acc[mi][ni], 0, 0, 0);
  }
#pragma unroll
  for (int mi = 0; mi < 2; ++mi)
#pragma unroll
    for (int ni = 0; ni < 2; ++ni)
#pragma unroll
      for (int j = 0; j < 4; ++j) {
        int row = m0 + wm * 32 + mi * 16 + (lane >> 4) * 4 + j;
        int col = n0 + wn * 32 + ni * 16 + (lane & 15);
        if (row < M && col < N) {
          float val = acc[mi][ni][j] * alpha;
          if (Dm) val += Dm[(size_t)row * ldd + col];
          size_t idx = (size_t)cbase + (size_t)row * ldc + col;
          if (OBF) ((unsigned short*)Cv)[idx] = f2bf(val);
          else     ((float*)Cv)[idx] = val;
        }
      }
}

template <bool OBF>
__global__ __launch_bounds__(256) void k_gemm_small(
    const float* __restrict__ A, int lda, long sA1, long sA2,
    const float* __restrict__ Bt, int ldb, long sB1, long sB2,
    void* __restrict__ Cv, int ldc, long sC1, long sC2,
    const float* __restrict__ Dm, int ldd,
    int M, int Mv, int N, int K, float alpha, int Z2) {
  int z = blockIdx.z, z1 = z / Z2, z2 = z - z1 * Z2;
  __shared__ short As[64 * 40];
  __shared__ short Bs[64 * 40];
  gemm64_body<OBF>(A + z1 * sA1 + z2 * sA2, lda, Bt + z1 * sB1 + z2 * sB2, ldb,
                   Cv, ldc, z1 * sC1 + z2 * sC2, Dm, ldd, M, Mv, N, K, alpha,
                   blockIdx.x * 64, blockIdx.y * 64, As, Bs);
}

// W_eff = W + (1/12) Bx@Ax : three GEMMs in one launch (z selects k/v/o)
__global__ __launch_bounds__(256) void k_weff(
    const float* __restrict__ Bk, const float* __restrict__ Bv, const float* __restrict__ Bo,
    const float* __restrict__ akT, const float* __restrict__ avT, const float* __restrict__ aoT,
    const float* __restrict__ Wk, const float* __restrict__ Wv, const float* __restrict__ Wo,
    float* __restrict__ weff, float alpha) {
  int z = blockIdx.z;
  const float* A  = z == 0 ? Bk : (z == 1 ? Bv : Bo);
  const float* Bt = z == 0 ? akT : (z == 1 ? avT : aoT);
  const float* Dm = z == 0 ? Wk : (z == 1 ? Wv : Wo);
  __shared__ short As[64 * 40];
  __shared__ short Bs[64 * 40];
  gemm64_body<false>(A, 192, Bt, 192, weff + (size_t)z * 1048576, 1024, 0, Dm, 1024,
                     1024, 1024, 1024, 192, alpha, blockIdx.x * 64, blockIdx.y * 64, As, Bs);
}

// ---------------- mu/alpha/beta per (b,h,s), with qmean GEMM fused ----------------
__global__ void k_mubeta(const float* __restrict__ hssum, const float* __restrict__ Wq,
                         const float* __restrict__ kv,
                         const int* __restrict__ sb, const int* __restrict__ sn,
                         const float* __restrict__ csf_p,
                         float* __restrict__ alphav, float* __restrict__ betav) {
  int h = blockIdx.x, b = blockIdx.y;
  int t = threadIdx.x;                       // 128 threads
  __shared__ float qp[64];
  {
    int hd = t >> 1, half = t & 1;
    const float* wr = Wq + (size_t)(h * 64 + hd) * D_ + half * 512;
    const float* hp = hssum + b * D_ + half * 512;
    float s = 0.f;
    for (int d = 0; d < 512; d += 4) {
      f4 w = *(const f4*)(wr + d);
      f4 x = *(const f4*)(hp + d);
      s += w[0] * x[0] + w[1] * x[1] + w[2] * x[2] + w[3] * x[3];
    }
    s += __shfl_xor(s, 1, 64);
    if (half == 0) qp[hd] = s * (1.f / 4096.f);
  }
  __syncthreads();
  int s = t;
  if (s >= SP_) return;
  const float* kp = kv + ((size_t)(b * SP_ + s)) * 2048 + h * HD_;
  float mu = 0.f;
#pragma unroll 8
  for (int hd = 0; hd < HD_; ++hd) mu += qp[hd] * kp[hd];
  mu *= 0.125f;
  bool subj = false;
  for (int i = 0; i < NSUBJ_; ++i) subj = subj || (sb[i] == b && sn[i] == s);
  float csf = *csf_p;
  int c = b * NC_ + h * SP_ + s;
  alphav[c] = subj ? csf : 1.f;
  betav[c] = (s >= S_) ? -1e30f : (subj ? -mu * csf : 0.f);
}

// ---------------- big score GEMM 256x320, 8-phase schedule ----------------
// waves 2M x 4N, wave tile 128x80 (one head per wave). XOR chunk swizzle.
// Per K-tile: 4 phases {ds_read subtile; [stage burst]; barrier; setprio MFMA; barrier}.
// Whole-tile wait invariant: counted vmcnt(5) at P0 (after 5-load burst) proves
// tile kt fully staged; barrier orders cross-wave.
__global__ __launch_bounds__(512, 2) void k_score_big(
    const unsigned short* __restrict__ hsb, const unsigned short* __restrict__ Mt,
    const float* __restrict__ alphav, const float* __restrict__ betav,
    unsigned short* __restrict__ P) {
  extern __shared__ short lds[];
  const int ASZ = 256 * 64;   // shorts
  const int BSZ = 320 * 64;
  int id = blockIdx.x;
  int x = id & 7, idp = id >> 3;
  int nt = idp & 3;
  int pid = (idp >> 2) * 8 + x;    // [0,128)
  int b = pid >> 4, mt = pid & 15;
  int m0 = mt * 256, n0 = nt * 320;

  const unsigned short* Ab = hsb + (size_t)b * LQ_ * D_;
  const unsigned short* Bb = Mt + (size_t)b * NC_ * D_;
  const float* alp = alphav + b * NC_;
  const float* bet = betav + b * NC_;
  unsigned short* Pb = P + (size_t)b * LQ_ * NC_;

  int t = threadIdx.x, lane = t & 63, wid = t >> 6;   // 8 waves
  int wm = wid >> 2, wn = wid & 3;
  int r = lane & 15, q = lane >> 4;
  f4 acc[8][5] = {};

  auto SA = [&](int bf, int k0, int p) {   // one 64-row slab of A (1 load/thread)
    int cb = p * 512 + wid * 64;
    int cc = cb + lane;
    int row = cc >> 3, col = ((cc & 7) ^ (row & 7)) * 8;
    gload16(Ab + (size_t)(m0 + row) * D_ + k0 + col, (char*)(lds + bf * ASZ) + cb * 16);
  };
  auto SB = [&](int bf, int k0, int p) {
    int cb = p * 512 + wid * 64;
    int cc = cb + lane;
    int row = cc >> 3, col = ((cc & 7) ^ (row & 7)) * 8;
    gload16(Bb + (size_t)(n0 + row) * D_ + k0 + col, (char*)(lds + 2 * ASZ + bf * BSZ) + cb * 16);
  };

  // prologue: tile 0 fully staged (9 loads/thread), no wait needed yet
#pragma unroll
  for (int p = 0; p < 4; ++p) SA(0, 0, p);
#pragma unroll
  for (int p = 0; p < 5; ++p) SB(0, 0, p);

  for (int kt = 0; kt < 16; ++kt) {
    int cur = kt & 1;
    const short* Ar = lds + cur * ASZ;
    const short* Br = lds + 2 * ASZ + cur * BSZ;
    int k1 = (kt + 1) * 64;
    bool pre = kt < 15;
    int co0 = (q ^ (lane & 7)) * 8;
    int co1 = ((4 + q) ^ (lane & 7)) * 8;
    short8 fb[5], fa[4];

    // ---- P0: stage A-slabs+B0 of kt+1; counted wait; read fb(kk0)+fa(kk0,lo) ----
    if (pre) {
      SA(cur ^ 1, k1, 0); SA(cur ^ 1, k1, 1); SA(cur ^ 1, k1, 2); SA(cur ^ 1, k1, 3);
      SB(cur ^ 1, k1, 0);
      asm volatile("s_waitcnt vmcnt(5)" ::: "memory");   // tile kt complete
    } else {
      asm volatile("s_waitcnt vmcnt(0)" ::: "memory");
    }
    __builtin_amdgcn_s_barrier();
#pragma unroll
    for (int ni = 0; ni < 5; ++ni) fb[ni] = *(const short8*)(Br + (wn * 80 + ni * 16 + r) * 64 + co0);
#pragma unroll
    for (int mi = 0; mi < 4; ++mi) fa[mi] = *(const short8*)(Ar + (wm * 128 + mi * 16 + r) * 64 + co0);
    __builtin_amdgcn_s_setprio(1);
#pragma unroll
    for (int mi = 0; mi < 4; ++mi)
#pragma unroll
      for (int ni = 0; ni < 5; ++ni)
        acc[mi][ni] = __builtin_amdgcn_mfma_f32_16x16x32_bf16(fa[mi], fb[ni], acc[mi][ni], 0, 0, 0);
    __builtin_amdgcn_s_setprio(0);
    __builtin_amdgcn_s_barrier();

    // ---- P1: read fa(kk0,hi); stage B1-4 of kt+1 ----
#pragma unroll
    for (int mi = 0; mi < 4; ++mi) fa[mi] = *(const short8*)(Ar + (wm * 128 + (4 + mi) * 16 + r) * 64 + co0);
    if (pre) { SB(cur ^ 1, k1, 1); SB(cur ^ 1, k1, 2); SB(cur ^ 1, k1, 3); SB(cur ^ 1, k1, 4); }
    __builtin_amdgcn_s_barrier();
    __builtin_amdgcn_s_setprio(1);
#pragma unroll
    for (int mi = 0; mi < 4; ++mi)
#pragma unroll
      for (int ni = 0; ni < 5; ++ni)
        acc[4 + mi][ni] = __builtin_amdgcn_mfma_f32_16x16x32_bf16(fa[mi], fb[ni], acc[4 + mi][ni], 0, 0, 0);
    __builtin_amdgcn_s_setprio(0);
    __builtin_amdgcn_s_barrier();

    // ---- P2: read fb(kk1)+fa(kk1,lo) ----
#pragma unroll
    for (int ni = 0; ni < 5; ++ni) fb[ni] = *(const short8*)(Br + (wn * 80 + ni * 16 + r) * 64 + co1);
#pragma unroll
    for (int mi = 0; mi < 4; ++mi) fa[mi] = *(const short8*)(Ar + (wm * 128 + mi * 16 + r) * 64 + co1);
    __builtin_amdgcn_s_barrier();
    __builtin_amdgcn_s_setprio(1);
#pragma unroll
    for (int mi = 0; mi < 4; ++mi)
#pragma unroll
      for (int ni = 0; ni < 5; ++ni)
        acc[mi][ni] = __builtin_amdgcn_mfma_f32_16x16x32_bf16(fa[mi], fb[ni], acc[mi][ni], 0, 0, 0);
    __builtin_amdgcn_s_setprio(0);
    __builtin_amdgcn_s_barrier();

    // ---- P3: read fa(kk1,hi) ----
#pragma unroll
    for (int mi = 0; mi < 4; ++mi) fa[mi] = *(const short8*)(Ar + (wm * 128 + (4 + mi) * 16 + r) * 64 + co1);
    __builtin_amdgcn_s_barrier();
    __builtin_amdgcn_s_setprio(1);
#pragma unroll
    for (int mi = 0; mi < 4; ++mi)
#pragma unroll
      for (int ni = 0; ni < 5; ++ni)
        acc[4 + mi][ni] = __builtin_amdgcn_mfma_f32_16x16x32_bf16(fa[mi], fb[ni], acc[4 + mi][ni], 0, 0, 0);
    __builtin_amdgcn_s_setprio(0);
    __builtin_amdgcn_s_barrier();
  }

  // epilogue: alpha*score + beta, per-head softmax (wave owns one 80-col head)
  float al[5], be[5];
#pragma unroll
  for (int ni = 0; ni < 5; ++ni) {
    int cc = n0 + wn * 80 + ni * 16 + (lane & 15);
    al[ni] = alp[cc]; be[ni] = bet[cc];
  }
#pragma unroll
  for (int mi = 0; mi < 8; ++mi) {
#pragma unroll
    for (int j = 0; j < 4; ++j) {
      float v[5];
      float m = -3.0e38f;
#pragma unroll
      for (int ni = 0; ni < 5; ++ni) { v[ni] = acc[mi][ni][j] * al[ni] + be[ni]; m = fmaxf(m, v[ni]); }
#pragma unroll
      for (int off = 1; off < 16; off <<= 1) m = fmaxf(m, __shfl_xor(m, off, 64));
      float ssum = 0.f;
#pragma unroll
      for (int ni = 0; ni < 5; ++ni) { v[ni] = __expf(v[ni] - m); ssum += v[ni]; }
#pragma unroll
      for (int off = 1; off < 16; off <<= 1) ssum += __shfl_xor(ssum, off, 64);
      float inv = 1.f / ssum;
      int row = m0 + wm * 128 + mi * 16 + (lane >> 4) * 4 + j;
      size_t rb = (size_t)row * NC_ + n0 + wn * 80 + (lane & 15);
#pragma unroll
      for (int ni = 0; ni < 5; ++ni)
        Pb[rb + ni * 16] = f2bf(v[ni] * inv);
    }
  }
}

// ---------------- fallback score GEMM (fp32 A, reg-staged), 128x160, 256 thr ----------------
__global__ __launch_bounds__(256) void k_score_f32(
    const float* __restrict__ hs, const unsigned short* __restrict__ Mt,
    const float* __restrict__ alphav, const float* __restrict__ betav,
    unsigned short* __restrict__ P) {
  int id = blockIdx.x;
  int x = id & 7, idp = id >> 3;
  int n_t = idp & 7;
  int pid = (idp >> 3) * 8 + x;
  int b = pid >> 5, m_t = pid & 31;
  int m0 = m_t * 128, n0 = n_t * 160;
  const float* Af = hs + (size_t)b * LQ_ * D_;
  const unsigned short* Bb = Mt + (size_t)b * NC_ * D_;
  const float* alp = alphav + b * NC_;
  const float* bet = betav + b * NC_;
  unsigned short* Pb = P + (size_t)b * LQ_ * NC_;
  __shared__ short As[128 * 64];
  __shared__ short Bs[160 * 64];
  int t = threadIdx.x, lane = t & 63, wid = t >> 6;
  int wm = wid >> 1, wn = wid & 1;
  int srow = lane >> 3;
  int schunk = (lane & 7) ^ srow;
  f4 acc[4][5] = {};
  for (int k0 = 0; k0 < D_; k0 += 64) {
    __syncthreads();
    for (int i = wid; i < 20; i += 4)
      gload16(Bb + (size_t)(n0 + i * 8 + srow) * D_ + k0 + schunk * 8, (char*)Bs + i * 1024);
    int arow = t >> 3, ac = t & 7;
    int awc = ac ^ (arow & 7);
#pragma unroll
    for (int p = 0; p < 4; ++p) {
      int row = p * 32 + arow;
      const float* src = Af + (size_t)(m0 + row) * D_ + k0 + ac * 8;
      f4 v0 = *(const f4*)src;
      f4 v1 = *(const f4*)(src + 4);
      us8 u;
#pragma unroll
      for (int j = 0; j < 4; ++j) { u[j] = f2bf(v0[j]); u[4 + j] = f2bf(v1[j]); }
      *(us8*)(As + row * 64 + awc * 8) = u;
    }
    __syncthreads();
#pragma unroll
    for (int kk = 0; kk < 2; ++kk) {
      int co = ((kk * 4 + (lane >> 4)) ^ (lane & 7)) * 8;
      short8 fa[4], fb[5];
#pragma unroll
      for (int mi = 0; mi < 4; ++mi)
        fa[mi] = *(const short8*)(As + (wm * 64 + mi * 16 + (lane & 15)) * 64 + co);
#pragma unroll
      for (int ni = 0; ni < 5; ++ni)
        fb[ni] = *(const short8*)(Bs + (wn * 80 + ni * 16 + (lane & 15)) * 64 + co);
#pragma unroll
      for (int mi = 0; mi < 4; ++mi)
#pragma unroll
        for (int ni = 0; ni < 5; ++ni)
          acc[mi][ni] = __builtin_amdgcn_mfma_f32_16x16x32_bf16(fa[mi], fb[ni], acc[mi][ni], 0, 0, 0);
    }
  }
  float al[5], be[5];
#pragma unroll
  for (int ni = 0; ni < 5; ++ni) {
    int cc = n0 + wn * 80 + ni * 16 + (lane & 15);
    al[ni] = alp[cc]; be[ni] = bet[cc];
  }
#pragma unroll
  for (int mi = 0; mi < 4; ++mi) {
#pragma unroll
    for (int j = 0; j < 4; ++j) {
      float v[5];
      float m = -3.0e38f;
#pragma unroll
      for (int ni = 0; ni < 5; ++ni) { v[ni] = acc[mi][ni][j] * al[ni] + be[ni]; m = fmaxf(m, v[ni]); }
#pragma unroll
      for (int off = 1; off < 16; off <<= 1) m = fmaxf(m, __shfl_xor(m, off, 64));
      float ssum = 0.f;
#pragma unroll
      for (int ni = 0; ni < 5; ++ni) { v[ni] = __expf(v[ni] - m); ssum += v[ni]; }
#pragma unroll
      for (int off = 1; off < 16; off <<= 1) ssum += __shfl_xor(ssum, off, 64);
      float inv = 1.f / ssum;
      int row = m0 + wm * 64 + mi * 16 + (lane >> 4) * 4 + j;
      size_t rb = (size_t)row * NC_ + n0 + wn * 80 + (lane & 15);
#pragma unroll
      for (int ni = 0; ni < 5; ++ni)
        Pb[rb + ni * 16] = f2bf(v[ni] * inv);
    }
  }
}

// ---------------- big out GEMM 256x256, 8-phase: out = P @ Ut^T + bo ----------------
__global__ __launch_bounds__(512, 2) void k_out_big(
    const unsigned short* __restrict__ P, const unsigned short* __restrict__ Ut,
    const float* __restrict__ bo, float* __restrict__ out) {
  extern __shared__ short lds[];
  const int ASZ = 256 * 64;
  int id = blockIdx.x;
  int x = id & 7, idp = id >> 3;
  int nt = idp & 3;
  int pid = (idp >> 2) * 8 + x;
  int b = pid >> 4, mt = pid & 15;
  int m0 = mt * 256, n0 = nt * 256;

  const unsigned short* Ab = P + (size_t)b * LQ_ * NC_;
  const unsigned short* Bb = Ut + (size_t)b * D_ * NC_;
  float* ob = out + (size_t)b * LQ_ * D_;

  int t = threadIdx.x, lane = t & 63, wid = t >> 6;
  int wm = wid >> 2, wn = wid & 3;
  int r = lane & 15, q = lane >> 4;
  f4 acc[8][4] = {};
  const int T = NC_ / 64;   // 20

  auto SA = [&](int bf, int k0, int p) {
    int cb = p * 512 + wid * 64;
    int cc = cb + lane;
    int row = cc >> 3, col = ((cc & 7) ^ (row & 7)) * 8;
    gload16(Ab + (size_t)(m0 + row) * NC_ + k0 + col, (char*)(lds + bf * ASZ) + cb * 16);
  };
  auto SB = [&](int bf, int k0, int p) {
    int cb = p * 512 + wid * 64;
    int cc = cb + lane;
    int row = cc >> 3, col = ((cc & 7) ^ (row & 7)) * 8;
    gload16(Bb + (size_t)(n0 + row) * NC_ + k0 + col, (char*)(lds + 2 * ASZ + bf * ASZ) + cb * 16);
  };

#pragma unroll
  for (int p = 0; p < 4; ++p) SA(0, 0, p);
#pragma unroll
  for (int p = 0; p < 4; ++p) SB(0, 0, p);

  for (int kt = 0; kt < T; ++kt) {
    int cur = kt & 1;
    const short* Ar = lds + cur * ASZ;
    const short* Br = lds + 2 * ASZ + cur * ASZ;
    int k1 = (kt + 1) * 64;
    bool pre = kt + 1 < T;
    int co0 = (q ^ (lane & 7)) * 8;
    int co1 = ((4 + q) ^ (lane & 7)) * 8;
    short8 fb[4], fa[4];

    // ---- P0 ----
    if (pre) {
      SA(cur ^ 1, k1, 0); SA(cur ^ 1, k1, 1); SA(cur ^ 1, k1, 2); SA(cur ^ 1, k1, 3);
      asm volatile("s_waitcnt vmcnt(4)" ::: "memory");
    } else {
      asm volatile("s_waitcnt vmcnt(0)" ::: "memory");
    }
    __builtin_amdgcn_s_barrier();
#pragma unroll
    for (int ni = 0; ni < 4; ++ni) fb[ni] = *(const short8*)(Br + (wn * 64 + ni * 16 + r) * 64 + co0);
#pragma unroll
    for (int mi = 0; mi < 4; ++mi) fa[mi] = *(const short8*)(Ar + (wm * 128 + mi * 16 + r) * 64 + co0);
    __builtin_amdgcn_s_setprio(1);
#pragma unroll
    for (int mi = 0; mi < 4; ++mi)
#pragma unroll
      for (int ni = 0; ni < 4; ++ni)
        acc[mi][ni] = __builtin_amdgcn_mfma_f32_16x16x32_bf16(fa[mi], fb[ni], acc[mi][ni], 0, 0, 0);
    __builtin_amdgcn_s_setprio(0);
    __builtin_amdgcn_s_barrier();

    // ---- P1 ----
#pragma unroll
    for (int mi = 0; mi < 4; ++mi) fa[mi] = *(const short8*)(Ar + (wm * 128 + (4 + mi) * 16 + r) * 64 + co0);
    if (pre) { SB(cur ^ 1, k1, 0); SB(cur ^ 1, k1, 1); SB(cur ^ 1, k1, 2); SB(cur ^ 1, k1, 3); }
    __builtin_amdgcn_s_barrier();
    __builtin_amdgcn_s_setprio(1);
#pragma unroll
    for (int mi = 0; mi < 4; ++mi)
#pragma unroll
      for (int ni = 0; ni < 4; ++ni)
        acc[4 + mi][ni] = __builtin_amdgcn_mfma_f32_16x16x32_bf16(fa[mi], fb[ni], acc[4 + mi][ni], 0, 0, 0);
    __builtin_amdgcn_s_setprio(0);
    __builtin_amdgcn_s_barrier();

    // ---- P2 ----
#pragma unroll
    for (int ni = 0; ni < 4; ++ni) fb[ni] = *(const short8*)(Br + (wn * 64 + ni * 16 + r) * 64 + co1);
#pragma unroll
    for (int mi = 0; mi < 4; ++mi) fa[mi] = *(const short8*)(Ar + (wm * 128 + mi * 16 + r) * 64 + co1);
    __builtin_amdgcn_s_barrier();
    __builtin_amdgcn_s_setprio(1);
#pragma unroll
    for (int mi = 0; mi < 4; ++mi)
#pragma unroll
      for (int ni = 0; ni < 4; ++ni)
        acc[mi][ni] = __builtin_amdgcn_mfma_f32_16x16x32_bf16(fa[mi], fb[ni], acc[mi][ni], 0, 0, 0);
    __builtin_amdgcn_s_setprio(0);
    __builtin_amdgcn_s_barrier();

    // ---- P3 ----
#pragma unroll
    for (int mi = 0; mi < 4; ++mi) fa[mi] = *(const short8*)(Ar + (wm * 128 + (4 + mi) * 16 + r) * 64 + co1);
    __builtin_amdgcn_s_barrier();
    __builtin_amdgcn_s_setprio(1);
#pragma unroll
    for (int mi = 0; mi < 4; ++mi)
#pragma unroll
      for (int ni = 0; ni < 4; ++ni)
        acc[4 + mi][ni] = __builtin_amdgcn_mfma_f32_16x16x32_bf16(fa[mi], fb[ni], acc[4 + mi][ni], 0, 0, 0);
    __builtin_amdgcn_s_setprio(0);
    __builtin_amdgcn_s_barrier();
  }

#pragma unroll
  for (int ni = 0; ni < 4; ++ni) {
    int col = n0 + wn * 64 + ni * 16 + (lane & 15);
    float bov = bo[col];
#pragma unroll
    for (int mi = 0; mi < 8; ++mi)
#pragma unroll
      for (int j = 0; j < 4; ++j) {
        int row = m0 + wm * 128 + mi * 16 + (lane >> 4) * 4 + j;
        ob[(size_t)row * D_ + col] = acc[mi][ni][j] + bov;
      }
  }
}

extern "C" void kernel_launch(void* const* d_in, const int* in_sizes, int n_in,
                              void* d_out, int out_size, void* d_ws, size_t ws_size,
                              hipStream_t stream) {
  const float* hs  = (const float*)d_in[0];
  const float* ehs = (const float*)d_in[1];
  const float* Wq  = (const float*)d_in[2];
  const float* Wk  = (const float*)d_in[3];
  const float* Wv  = (const float*)d_in[4];
  const float* Wo  = (const float*)d_in[5];
  const float* bo  = (const float*)d_in[6];
  const float* Ak  = (const float*)d_in[7];
  const float* Bk  = (const float*)d_in[8];
  const float* Av  = (const float*)d_in[9];
  const float* Bv  = (const float*)d_in[10];
  const float* Ao  = (const float*)d_in[11];
  const float* Bo  = (const float*)d_in[12];
  const float* csf = (const float*)d_in[13];
  const int*   sb  = (const int*)d_in[14];
  const int*   sn  = (const int*)d_in[15];
  float* out = (float*)d_out;

  hipFuncSetAttribute(reinterpret_cast<const void*>(k_score_big),
                      hipFuncAttributeMaxDynamicSharedMemorySize, 147456);
  hipFuncSetAttribute(reinterpret_cast<const void*>(k_out_big),
                      hipFuncAttributeMaxDynamicSharedMemorySize, 131072);

  char* ws = (char*)d_ws;
  unsigned short* P  = (unsigned short*)ws;                   // 83,886,080
  unsigned short* Mt = (unsigned short*)(ws + 83886080);      // 20,971,520
  unsigned short* Ut = (unsigned short*)(ws + 104857600);     // 20,971,520
  const size_t NEED_HSB = 125829120ULL + 67108864ULL + 81920ULL; // 193,019,904
  bool useHsb = ws_size >= NEED_HSB;
  unsigned short* hsb = useHsb ? (unsigned short*)(ws + 125829120) : nullptr;
  char* tail = useHsb ? (ws + 192937984) : (ws + 125829120);
  float* alphav = (float*)tail;
  float* betav  = (float*)(tail + 40960);
  // temporaries overlapped into P's region (all dead before k_score writes P):
  float* kvbuf = (float*)(ws + 0);            //  5,242,880  [b][80][2048] (k|v)
  float* weff  = (float*)(ws + 5242880);      // 12,582,912  [wkE;wvE;woE]
  float* wqT   = (float*)(ws + 17825792);     //  4,194,304
  float* aT    = (float*)(ws + 22020096);     //  2,359,296
  float* part  = (float*)(ws + 24379392);     //  2,097,152
  float* hssum = (float*)(ws + 26476544);     //     32,768

  float* woE = weff + 2097152;
  float* akT = aT;
  float* avT = aT + 196608;
  float* aoT = aT + 393216;

  const float LS = 16.0f / 192.0f;

  // hs row-sums (deterministic two-stage) + bf16 conversion of hs
  k_hssum<<<dim3(64, 8), 256, 0, stream>>>(hs, part, hsb);
  k_hsred<<<32, 256, 0, stream>>>(part, hssum);

  // all transposes in one launch
  k_tr4<<<dim3(32, 32, 4), 256, 0, stream>>>(Wq, Ak, Av, Ao, wqT, akT, avT, aoT);

  // W_eff (k,v,o) in one launch
  k_weff<<<dim3(16, 16, 3), 256, 0, stream>>>(Bk, Bv, Bo, akT, avT, aoT, Wk, Wv, Wo, weff, LS);

  // [k|v] = ehs @ [wkE;wvE]^T : N=2048, C row-stride 2048
  k_gemm_small<false><<<dim3(2, 32, 8), 256, 0, stream>>>(
      ehs, 1024, 77L * 1024, 0, weff, 1024, 0, 0, kvbuf, 2048, 80L * 2048, 0, nullptr, 0,
      80, 77, 2048, 1024, 1.f, 1);

  // Mt[b,h] = 0.125 * k_bh @ Wq_h   (bf16, [b][h*80+s][d])
  k_gemm_small<true><<<dim3(2, 16, 128), 256, 0, stream>>>(
      kvbuf, 2048, 80L * 2048, 64L, wqT, 1024, 0, 64L,
      Mt, 1024, (long)NC_ * 1024, 80L * 1024, nullptr, 0,
      80, 80, 1024, 64, 0.125f, 16);

  // Ut[b,h] = Wo_eff_h @ v_bh^T   (bf16, [b][e][h*80+s])
  k_gemm_small<true><<<dim3(16, 2, 128), 256, 0, stream>>>(
      woE, 1024, 0, 64L, kvbuf + 1024, 2048, 80L * 2048, 64L,
      Ut, NC_, 1024L * NC_, 80L, nullptr, 0,
      1024, 1024, 80, 64, 1.f, 16);

  // per-(b,h,s) column mean (qmean fused) + subject alpha/beta
  k_mubeta<<<dim3(16, 8), 128, 0, stream>>>(hssum, Wq, kvbuf, sb, sn, csf, alphav, betav);

  // big fused GEMMs
  if (useHsb)
    k_score_big<<<512, 512, 147456, stream>>>(hsb, Mt, alphav, betav, P);
  else
    k_score_f32<<<2048, 256, 0, stream>>>(hs, Mt, alphav, betav, P);
  k_out_big<<<512, 512, 131072, stream>>>(P, Ut, bo, out);

  (void)in_sizes; (void)n_in; (void)out_size; (void)ws_size;
}